// Round 1
// baseline (2048.493 us; speedup 1.0000x reference)
//
#include <hip/hip_runtime.h>
#include <math.h>

#define H 128
#define NEGS 0.01f

__device__ __forceinline__ float lrelu(float x){ return x >= 0.f ? x : NEGS*x; }
__device__ __forceinline__ float eluf(float x){ return x > 0.f ? x : expf(x)-1.f; }
__device__ __forceinline__ float sigm(float x){ return 1.f/(1.f+expf(-x)); }
// monotonic float<->unsigned encoding for atomicMax on floats
__device__ __forceinline__ unsigned fenc(float f){
  unsigned u = __float_as_uint(f);
  return (u & 0x80000000u) ? ~u : (u | 0x80000000u);
}
__device__ __forceinline__ float fdec(unsigned v){
  return __uint_as_float((v & 0x80000000u) ? (v ^ 0x80000000u) : ~v);
}
__device__ __forceinline__ float wred(float v){
  #pragma unroll
  for (int off = 32; off > 0; off >>= 1) v += __shfl_xor(v, off, 64);
  return v;
}

// x[i,t] = lrelu(node_attr[i]*W_lin1[t] + b_lin1[t])
__global__ void k_node_init(const float* __restrict__ na, const float* __restrict__ wl,
                            const float* __restrict__ bl, float* __restrict__ x, int n){
  int idx = blockIdx.x*blockDim.x + threadIdx.x;
  if (idx >= n*H) return;
  int i = idx >> 7, t = idx & 127;
  x[idx] = lrelu(na[i]*wl[t] + bl[t]);
}

// Y[i*ldy + m] = sum_k act(X[i*128+k]) * W[m*ldw + k],  m in [0,128)
// block 256 thr, 32 nodes/block, K chunked by 64. elu_in: apply ELU to X.
__global__ __launch_bounds__(256)
void k_gemm128(const float* __restrict__ X, const float* __restrict__ W,
               float* __restrict__ Y, int n, int ldw, int ldy, int elu_in){
  __shared__ float Wt[64*132];   // Wt[k][m], stride 132
  __shared__ float Xs[64*36];    // Xs[k][node], stride 36
  int t = threadIdx.x;
  int i0 = blockIdx.x*32;
  int tm = t & 31, tn = t >> 5;  // tm: m/4, tn: node-group (4 nodes)
  float a00=0,a01=0,a02=0,a03=0, a10=0,a11=0,a12=0,a13=0;
  float a20=0,a21=0,a22=0,a23=0, a30=0,a31=0,a32=0,a33=0;
  for (int kc = 0; kc < 128; kc += 64){
    #pragma unroll
    for (int j = 0; j < 32; ++j){            // 8192 W elems
      int idx = j*256 + t;
      int m = idx >> 6, k = idx & 63;
      Wt[k*132 + m] = W[m*ldw + kc + k];
    }
    #pragma unroll
    for (int j = 0; j < 8; ++j){             // 2048 X elems
      int idx = j*256 + t;
      int node = idx >> 6, k = idx & 63;
      int i = i0 + node;
      float v = (i < n) ? X[(size_t)i*H + kc + k] : 0.f;
      if (elu_in) v = eluf(v);
      Xs[k*36 + node] = v;
    }
    __syncthreads();
    #pragma unroll 8
    for (int k = 0; k < 64; ++k){
      const float4 wv = *(const float4*)&Wt[k*132 + tm*4];
      const float4 xv = *(const float4*)&Xs[k*36 + tn*4];
      a00 += wv.x*xv.x; a01 += wv.x*xv.y; a02 += wv.x*xv.z; a03 += wv.x*xv.w;
      a10 += wv.y*xv.x; a11 += wv.y*xv.y; a12 += wv.y*xv.z; a13 += wv.y*xv.w;
      a20 += wv.z*xv.x; a21 += wv.z*xv.y; a22 += wv.z*xv.z; a23 += wv.z*xv.w;
      a30 += wv.w*xv.x; a31 += wv.w*xv.y; a32 += wv.w*xv.z; a33 += wv.w*xv.w;
    }
    __syncthreads();
  }
  float accm[4][4] = {{a00,a01,a02,a03},{a10,a11,a12,a13},{a20,a21,a22,a23},{a30,a31,a32,a33}};
  #pragma unroll
  for (int b = 0; b < 4; ++b){
    int i = i0 + tn*4 + b;
    if (i < n){
      float4 o = make_float4(accm[0][b], accm[1][b], accm[2][b], accm[3][b]);
      *(float4*)&Y[(size_t)i*ldy + tm*4] = o;
    }
  }
}

// per-node dots with one or two 128-vectors (one wave per node)
__global__ void k_rowdot2(const float* __restrict__ X, const float* __restrict__ v1,
                          const float* __restrict__ v2, float* __restrict__ o1,
                          float* __restrict__ o2, int n){
  int i = blockIdx.x*4 + (threadIdx.x >> 6);
  int lane = threadIdx.x & 63;
  if (i >= n) return;
  const float* xr = X + (size_t)i*H;
  float a = xr[lane]*v1[lane] + xr[lane+64]*v1[lane+64];
  float b = 0.f;
  if (v2) b = xr[lane]*v2[lane] + xr[lane+64]*v2[lane+64];
  a = wred(a);
  if (v2) b = wred(b);
  if (lane == 0){ o1[i] = a; if (v2) o2[i] = b; }
}

// GATEConv edge logits: lrelu( sum_h lrelu(xW1[s,h]+ea*W1[h,128]) * attl[h] + rdot[d] )
__global__ void k_edge_logit_gate(const float* __restrict__ xW1, const float* __restrict__ gateW1,
                                  const float* __restrict__ attl, const float* __restrict__ rdot,
                                  const float* __restrict__ ea, const int* __restrict__ src,
                                  const int* __restrict__ dst, float* __restrict__ logit,
                                  unsigned* __restrict__ segmax, int ne){
  int e = blockIdx.x*4 + (threadIdx.x >> 6);
  int lane = threadIdx.x & 63;
  if (e >= ne) return;
  int s = src[e], d = dst[e];
  float eav = ea[e];
  const float* xr = xW1 + (size_t)s*H;
  float p = 0.f;
  #pragma unroll
  for (int j = 0; j < 2; ++j){
    int h = lane + j*64;
    float v = lrelu(xr[h] + eav * gateW1[h*129 + 128]);
    p += v * attl[h];
  }
  p = wred(p);
  if (lane == 0){
    float l = lrelu(p + rdot[d]);
    logit[e] = l;
    atomicMax(&segmax[d], fenc(l));
  }
}

// GATConv edge logits: lrelu(ssrc[s] + sdst[d])
__global__ void k_edge_logit_gat(const float* __restrict__ ssrc, const float* __restrict__ sdst,
                                 const int* __restrict__ src, const int* __restrict__ dst,
                                 float* __restrict__ logit, unsigned* __restrict__ segmax, int ne){
  int e = blockIdx.x*blockDim.x + threadIdx.x;
  if (e >= ne) return;
  float l = lrelu(ssrc[src[e]] + sdst[dst[e]]);
  logit[e] = l;
  atomicMax(&segmax[dst[e]], fenc(l));
}

// logit -> exp(logit - segmax[dst]) in place; accumulate segsum
__global__ void k_edge_expsum(float* __restrict__ logit, const unsigned* __restrict__ segmax,
                              const int* __restrict__ dst, float* __restrict__ segsum, int ne){
  int e = blockIdx.x*blockDim.x + threadIdx.x;
  if (e >= ne) return;
  int d = dst[e];
  float ex = expf(logit[e] - fdec(segmax[d]));
  logit[e] = ex;
  atomicAdd(&segsum[d], ex);
}

// hb[i,t] = bias[t]
__global__ void k_binit(float* __restrict__ hb, const float* __restrict__ bias, int n){
  int idx = blockIdx.x*blockDim.x + threadIdx.x;
  if (idx >= n*H) return;
  hb[idx] = bias[idx & 127];
}

// hb[dst] += val[src] * (alpha/segsum[dst]), one wave per edge
__global__ void k_edge_scatter(const float* __restrict__ val, const float* __restrict__ alpha,
                               const float* __restrict__ segsum, const int* __restrict__ src,
                               const int* __restrict__ dst, float* __restrict__ hb, int ne){
  int e = blockIdx.x*4 + (threadIdx.x >> 6);
  int lane = threadIdx.x & 63;
  if (e >= ne) return;
  int s = src[e], d = dst[e];
  float w = alpha[e] / segsum[d];
  const float* vr = val + (size_t)s*H;
  float* hr = hb + (size_t)d*H;
  atomicAdd(&hr[lane],    vr[lane]*w);
  atomicAdd(&hr[lane+64], vr[lane+64]*w);
}

// GRUCell combine: x = relu((1-z)*n + z*x), gates from gi (input side), gh (hidden side)
__global__ void k_gru_combine(const float* __restrict__ gi, const float* __restrict__ gh,
                              const float* __restrict__ bih, const float* __restrict__ bhh,
                              float* __restrict__ x, int n){
  int idx = blockIdx.x*blockDim.x + threadIdx.x;
  if (idx >= n*H) return;
  int i = idx >> 7, t = idx & 127;
  const float* gir = gi + (size_t)i*384;
  const float* ghr = gh + (size_t)i*384;
  float ir = gir[t] + bih[t], iz = gir[t+128] + bih[t+128], in = gir[t+256] + bih[t+256];
  float hr = ghr[t] + bhh[t], hz = ghr[t+128] + bhh[t+128], hn = ghr[t+256] + bhh[t+256];
  float r = sigm(ir + hr), z = sigm(iz + hz);
  float nn = tanhf(in + r*hn);
  float xo = (1.f - z)*nn + z*x[idx];
  x[idx] = fmaxf(xo, 0.f);
}

// column partial sums of x over node chunks -> atomicAdd into outraw[128]
__global__ void k_colsum(const float* __restrict__ x, float* __restrict__ outraw,
                         int n, int chunk){
  int t = threadIdx.x; // 128
  int start = blockIdx.x*chunk;
  int end = min(start + chunk, n);
  float s = 0.f;
  for (int i = start; i < end; ++i) s += x[(size_t)i*H + t];
  if (s != 0.f || start < end) atomicAdd(&outraw[t], s);
}

// hidvec = relu(outraw); cdst = sum_t (hid @ molW.T)[t] * attdst[t]
__global__ void k_mol_prep(const float* __restrict__ outraw, const float* __restrict__ molW,
                           const float* __restrict__ attdst, float* __restrict__ hidvec,
                           float* __restrict__ cdst){
  __shared__ float hs[128];
  __shared__ float red[128];
  int t = threadIdx.x;
  float hv = fmaxf(outraw[t], 0.f);
  hs[t] = hv; hidvec[t] = hv;
  __syncthreads();
  float o = 0.f;
  for (int k = 0; k < 128; ++k) o += hs[k]*molW[t*128+k];
  red[t] = o * attdst[t];
  __syncthreads();
  for (int s = 64; s > 0; s >>= 1){
    if (t < s) red[t] += red[t+s];
    __syncthreads();
  }
  if (t == 0) cdst[0] = red[0];
}

// a[i] = lrelu(a[i] + cdst); atomicMax gmax
__global__ void k_mol_logit(float* __restrict__ a, const float* __restrict__ cdst,
                            unsigned* __restrict__ gmax, int n){
  int i = blockIdx.x*blockDim.x + threadIdx.x;
  if (i >= n) return;
  float l = lrelu(a[i] + cdst[0]);
  a[i] = l;
  atomicMax(gmax, fenc(l));
}

// a[i] = exp(a[i]-gmax); gsum += sum (wave-reduced)
__global__ void k_mol_exp(float* __restrict__ a, const unsigned* __restrict__ gmax,
                          float* __restrict__ gsum, int n){
  int i = blockIdx.x*blockDim.x + threadIdx.x;
  int lane = threadIdx.x & 63;
  float gm = fdec(gmax[0]);
  float ex = 0.f;
  if (i < n){ ex = expf(a[i] - gm); a[i] = ex; }
  float s = wred(ex);
  if (lane == 0) atomicAdd(gsum, s);
}

// num[t] += sum_i xs[i,t]*a[i] over node chunk
__global__ void k_mol_acc(const float* __restrict__ xs, const float* __restrict__ a,
                          float* __restrict__ num, int n, int chunk){
  int t = threadIdx.x; // 128
  int start = blockIdx.x*chunk;
  int end = min(start + chunk, n);
  float s = 0.f;
  for (int i = start; i < end; ++i) s += xs[(size_t)i*H + t]*a[i];
  atomicAdd(&num[t], s);
}

// final: h = elu(num/gsum + molb); out = relu(gru(h, hidvec)) -> d_out[128]
__global__ void k_mol_final(const float* __restrict__ num, const float* __restrict__ gsum,
                            const float* __restrict__ molb, const float* __restrict__ hidvec,
                            const float* __restrict__ Wih, const float* __restrict__ Whh,
                            const float* __restrict__ bih, const float* __restrict__ bhh,
                            float* __restrict__ out){
  __shared__ float hv[128], hd[128];
  int t = threadIdx.x;
  hv[t] = eluf(num[t]/gsum[0] + molb[t]);
  hd[t] = hidvec[t];
  __syncthreads();
  float gr = bih[t], gz = bih[t+128], gn = bih[t+256];
  float hr = bhh[t], hz = bhh[t+128], hn = bhh[t+256];
  for (int k = 0; k < 128; ++k){
    float h = hv[k], d = hd[k];
    gr += h*Wih[t*128+k];       gz += h*Wih[(t+128)*128+k]; gn += h*Wih[(t+256)*128+k];
    hr += d*Whh[t*128+k];       hz += d*Whh[(t+128)*128+k]; hn += d*Whh[(t+256)*128+k];
  }
  float r = sigm(gr+hr), z = sigm(gz+hz);
  float nn = tanhf(gn + r*hn);
  float o = (1.f-z)*nn + z*hd[t];
  out[t] = fmaxf(o, 0.f);
}

extern "C" void kernel_launch(void* const* d_in, const int* in_sizes, int n_in,
                              void* d_out, int out_size, void* d_ws, size_t ws_size,
                              hipStream_t stream){
  const float* node_attr = (const float*)d_in[0];
  const int*   eidx      = (const int*)d_in[1];
  const float* eattr     = (const float*)d_in[2];
  const float* W_lin1    = (const float*)d_in[3];
  const float* b_lin1    = (const float*)d_in[4];
  const float* gate_W1   = (const float*)d_in[5];
  const float* gate_W2   = (const float*)d_in[6];
  const float* gate_att_l= (const float*)d_in[7];
  const float* gate_att_r= (const float*)d_in[8];
  const float* gate_b    = (const float*)d_in[9];
  const float* g1_Wih    = (const float*)d_in[10];
  const float* g1_Whh    = (const float*)d_in[11];
  const float* g1_bih    = (const float*)d_in[12];
  const float* g1_bhh    = (const float*)d_in[13];
  const float* atom_W    = (const float*)d_in[14];
  const float* atom_as   = (const float*)d_in[15];
  const float* atom_ad   = (const float*)d_in[16];
  const float* atom_b    = (const float*)d_in[17];
  const float* g2_Wih    = (const float*)d_in[18];
  const float* g2_Whh    = (const float*)d_in[19];
  const float* g2_bih    = (const float*)d_in[20];
  const float* g2_bhh    = (const float*)d_in[21];
  const float* mol_W     = (const float*)d_in[22];
  const float* mol_as    = (const float*)d_in[23];
  const float* mol_ad    = (const float*)d_in[24];
  const float* mol_b     = (const float*)d_in[25];
  const float* gm_Wih    = (const float*)d_in[26];
  const float* gm_Whh    = (const float*)d_in[27];
  const float* gm_bih    = (const float*)d_in[28];
  const float* gm_bhh    = (const float*)d_in[29];

  const int n  = in_sizes[0];        // node_attr: [N,1]
  const int ne = in_sizes[1] / 2;    // edge_index: [2,E]
  const int* src = eidx;
  const int* dst = eidx + ne;

  // ---- workspace layout (floats). total ~46M floats = ~184 MB ----
  float* ws = (float*)d_ws;
  const size_t NH = (size_t)n * H;
  float* x    = ws;               // [N,H]  node features (updated in place by GRUs)
  float* t0   = ws + NH;          // [N,H]  xW1 / xt
  float* t1   = ws + 2*NH;        // [N,H]  xW2 / xs
  float* hbuf = ws + 3*NH;        // [N,H]  aggregation buffer
  float* gi   = ws + 4*NH;        // [N,384]
  float* gh   = t0;               // [N,384] aliases t0,t1,hbuf (dead at gh time)
  float* rdot = ws + 7*NH;        // [N]
  float* ssrc = rdot + n;         // [N]
  float* sdst = ssrc + n;         // [N]
  unsigned* segmax = (unsigned*)(sdst + n);   // [N]
  float* segsum = (float*)segmax + n;         // [N]
  float* ealpha = segsum + n;                 // [E] logits -> alpha in place
  float* outraw = ealpha + ne;                // [128]
  float* hidvec = outraw + 128;               // [128]
  float* cdstp  = hidvec + 128;               // [1]
  unsigned* gmax = (unsigned*)(cdstp + 1);    // [1]
  float* gsum   = (float*)gmax + 1;           // [1]
  float* numv   = gsum + 1;                   // [128]

  const int nh_blocks   = (n*H + 255)/256;
  const int gemm_blocks = (n + 31)/32;
  const int nwave4      = (n + 3)/4;
  const int ewave4      = (ne + 3)/4;
  const int ethr        = (ne + 255)/256;
  const int nthr        = (n + 255)/256;
  const int chunk       = (n + 255)/256;

  // ---- node init ----
  k_node_init<<<nh_blocks,256,0,stream>>>(node_attr, W_lin1, b_lin1, x, n);

  // ---- GATEConv ----
  k_gemm128<<<gemm_blocks,256,0,stream>>>(x, gate_W1, t0, n, 129, H, 0);   // xW1 (first 128 cols)
  k_gemm128<<<gemm_blocks,256,0,stream>>>(x, gate_W2, t1, n, 128, H, 0);   // xW2
  k_rowdot2<<<nwave4,256,0,stream>>>(x, gate_att_r, nullptr, rdot, nullptr, n);
  hipMemsetAsync(segmax, 0, (size_t)n*4, stream);
  hipMemsetAsync(segsum, 0, (size_t)n*4, stream);
  k_edge_logit_gate<<<ewave4,256,0,stream>>>(t0, gate_W1, gate_att_l, rdot, eattr,
                                             src, dst, ealpha, segmax, ne);
  k_edge_expsum<<<ethr,256,0,stream>>>(ealpha, segmax, dst, segsum, ne);
  k_binit<<<nh_blocks,256,0,stream>>>(hbuf, gate_b, n);
  k_edge_scatter<<<ewave4,256,0,stream>>>(t1, ealpha, segsum, src, dst, hbuf, ne);
  // GRU1: gi = elu(hbuf)@Wih.T ; gh = x@Whh.T ; combine -> x
  for (int c = 0; c < 3; ++c)
    k_gemm128<<<gemm_blocks,256,0,stream>>>(hbuf, g1_Wih + c*128*128, gi + c*128, n, 128, 384, 1);
  for (int c = 0; c < 3; ++c)
    k_gemm128<<<gemm_blocks,256,0,stream>>>(x, g1_Whh + c*128*128, gh + c*128, n, 128, 384, 0);
  k_gru_combine<<<nh_blocks,256,0,stream>>>(gi, gh, g1_bih, g1_bhh, x, n);

  // ---- GATConv ----
  k_gemm128<<<gemm_blocks,256,0,stream>>>(x, atom_W, t0, n, 128, H, 0);    // xt
  k_rowdot2<<<nwave4,256,0,stream>>>(t0, atom_as, atom_ad, ssrc, sdst, n);
  hipMemsetAsync(segmax, 0, (size_t)n*4, stream);
  hipMemsetAsync(segsum, 0, (size_t)n*4, stream);
  k_edge_logit_gat<<<ethr,256,0,stream>>>(ssrc, sdst, src, dst, ealpha, segmax, ne);
  k_edge_expsum<<<ethr,256,0,stream>>>(ealpha, segmax, dst, segsum, ne);
  k_binit<<<nh_blocks,256,0,stream>>>(hbuf, atom_b, n);
  k_edge_scatter<<<ewave4,256,0,stream>>>(t0, ealpha, segsum, src, dst, hbuf, ne);
  // GRU2
  for (int c = 0; c < 3; ++c)
    k_gemm128<<<gemm_blocks,256,0,stream>>>(hbuf, g2_Wih + c*128*128, gi + c*128, n, 128, 384, 1);
  for (int c = 0; c < 3; ++c)
    k_gemm128<<<gemm_blocks,256,0,stream>>>(x, g2_Whh + c*128*128, gh + c*128, n, 128, 384, 0);
  k_gru_combine<<<nh_blocks,256,0,stream>>>(gi, gh, g2_bih, g2_bhh, x, n);

  // ---- molecule readout ----
  hipMemsetAsync(outraw, 0, 128*4, stream);
  hipMemsetAsync(gmax, 0, 4, stream);
  hipMemsetAsync(gsum, 0, 4, stream);
  hipMemsetAsync(numv, 0, 128*4, stream);
  k_colsum<<<256,128,0,stream>>>(x, outraw, n, chunk);
  k_mol_prep<<<1,128,0,stream>>>(outraw, mol_W, mol_ad, hidvec, cdstp);
  k_gemm128<<<gemm_blocks,256,0,stream>>>(x, mol_W, t1, n, 128, H, 0);     // xs
  k_rowdot2<<<nwave4,256,0,stream>>>(t1, mol_as, nullptr, rdot, nullptr, n);
  k_mol_logit<<<nthr,256,0,stream>>>(rdot, cdstp, gmax, n);
  k_mol_exp<<<nthr,256,0,stream>>>(rdot, gmax, gsum, n);
  k_mol_acc<<<256,128,0,stream>>>(t1, rdot, numv, n, chunk);
  k_mol_final<<<1,128,0,stream>>>(numv, gsum, mol_b, hidvec,
                                  gm_Wih, gm_Whh, gm_bih, gm_bhh, (float*)d_out);
}

// Round 2
// 1624.755 us; speedup vs baseline: 1.2608x; 1.2608x over previous
//
#include <hip/hip_runtime.h>
#include <math.h>

#define H 128
#define NEGS 0.01f

__device__ __forceinline__ float lrelu(float x){ return x >= 0.f ? x : NEGS*x; }
__device__ __forceinline__ float eluf(float x){ return x > 0.f ? x : expf(x)-1.f; }
__device__ __forceinline__ float sigm(float x){ return 1.f/(1.f+expf(-x)); }
__device__ __forceinline__ float wred(float v){
  #pragma unroll
  for (int off = 32; off > 0; off >>= 1) v += __shfl_xor(v, off, 64);
  return v;
}
__device__ __forceinline__ float wredmax(float v){
  #pragma unroll
  for (int off = 32; off > 0; off >>= 1) v = fmaxf(v, __shfl_xor(v, off, 64));
  return v;
}
// monotonic float<->unsigned encoding for atomicMax on floats (mol softmax only)
__device__ __forceinline__ unsigned fenc(float f){
  unsigned u = __float_as_uint(f);
  return (u & 0x80000000u) ? ~u : (u | 0x80000000u);
}
__device__ __forceinline__ float fdec(unsigned v){
  return __uint_as_float((v & 0x80000000u) ? (v ^ 0x80000000u) : ~v);
}

// x[i,t] = lrelu(node_attr[i]*W_lin1[t] + b_lin1[t])
__global__ void k_node_init(const float* __restrict__ na, const float* __restrict__ wl,
                            const float* __restrict__ bl, float* __restrict__ x, int n){
  int idx = blockIdx.x*blockDim.x + threadIdx.x;
  if (idx >= n*H) return;
  int i = idx >> 7, t = idx & 127;
  x[idx] = lrelu(na[i]*wl[t] + bl[t]);
}

// Y[i*ldy + m] = sum_k act(X[i*128+k]) * W[m*ldw + k],  m in [0,128)
__global__ __launch_bounds__(256)
void k_gemm128(const float* __restrict__ X, const float* __restrict__ W,
               float* __restrict__ Y, int n, int ldw, int ldy, int elu_in){
  __shared__ float Wt[64*132];   // Wt[k][m], stride 132
  __shared__ float Xs[64*36];    // Xs[k][node], stride 36
  int t = threadIdx.x;
  int i0 = blockIdx.x*32;
  int tm = t & 31, tn = t >> 5;
  float a00=0,a01=0,a02=0,a03=0, a10=0,a11=0,a12=0,a13=0;
  float a20=0,a21=0,a22=0,a23=0, a30=0,a31=0,a32=0,a33=0;
  for (int kc = 0; kc < 128; kc += 64){
    #pragma unroll
    for (int j = 0; j < 32; ++j){
      int idx = j*256 + t;
      int m = idx >> 6, k = idx & 63;
      Wt[k*132 + m] = W[m*ldw + kc + k];
    }
    #pragma unroll
    for (int j = 0; j < 8; ++j){
      int idx = j*256 + t;
      int node = idx >> 6, k = idx & 63;
      int i = i0 + node;
      float v = (i < n) ? X[(size_t)i*H + kc + k] : 0.f;
      if (elu_in) v = eluf(v);
      Xs[k*36 + node] = v;
    }
    __syncthreads();
    #pragma unroll 8
    for (int k = 0; k < 64; ++k){
      const float4 wv = *(const float4*)&Wt[k*132 + tm*4];
      const float4 xv = *(const float4*)&Xs[k*36 + tn*4];
      a00 += wv.x*xv.x; a01 += wv.x*xv.y; a02 += wv.x*xv.z; a03 += wv.x*xv.w;
      a10 += wv.y*xv.x; a11 += wv.y*xv.y; a12 += wv.y*xv.z; a13 += wv.y*xv.w;
      a20 += wv.z*xv.x; a21 += wv.z*xv.y; a22 += wv.z*xv.z; a23 += wv.z*xv.w;
      a30 += wv.w*xv.x; a31 += wv.w*xv.y; a32 += wv.w*xv.z; a33 += wv.w*xv.w;
    }
    __syncthreads();
  }
  float accm[4][4] = {{a00,a01,a02,a03},{a10,a11,a12,a13},{a20,a21,a22,a23},{a30,a31,a32,a33}};
  #pragma unroll
  for (int b = 0; b < 4; ++b){
    int i = i0 + tn*4 + b;
    if (i < n){
      float4 o = make_float4(accm[0][b], accm[1][b], accm[2][b], accm[3][b]);
      *(float4*)&Y[(size_t)i*ldy + tm*4] = o;
    }
  }
}

// per-node dots with one or two 128-vectors (one wave per node)
__global__ void k_rowdot2(const float* __restrict__ X, const float* __restrict__ v1,
                          const float* __restrict__ v2, float* __restrict__ o1,
                          float* __restrict__ o2, int n){
  int i = blockIdx.x*4 + (threadIdx.x >> 6);
  int lane = threadIdx.x & 63;
  if (i >= n) return;
  const float* xr = X + (size_t)i*H;
  float a = xr[lane]*v1[lane] + xr[lane+64]*v1[lane+64];
  float b = 0.f;
  if (v2) b = xr[lane]*v2[lane] + xr[lane+64]*v2[lane+64];
  a = wred(a);
  if (v2) b = wred(b);
  if (lane == 0){ o1[i] = a; if (v2) o2[i] = b; }
}

// ---------------- CSR build (dst-grouped edge lists) ----------------
__global__ void k_hist(const int* __restrict__ dst, int* __restrict__ deg, int ne){
  int e = blockIdx.x*blockDim.x + threadIdx.x;
  if (e < ne) atomicAdd(&deg[dst[e]], 1);
}
__global__ void k_scan1(const int* __restrict__ deg, int* __restrict__ bsum, int n){
  __shared__ int sd[256];
  int i = blockIdx.x*256 + threadIdx.x;
  sd[threadIdx.x] = (i < n) ? deg[i] : 0;
  __syncthreads();
  for (int s = 128; s > 0; s >>= 1){
    if (threadIdx.x < s) sd[threadIdx.x] += sd[threadIdx.x+s];
    __syncthreads();
  }
  if (threadIdx.x == 0) bsum[blockIdx.x] = sd[0];
}
__global__ void k_scan2(int* __restrict__ bsum, int nb){   // nb <= 256, single block
  __shared__ int sd[256];
  int t = threadIdx.x;
  int v = (t < nb) ? bsum[t] : 0;
  sd[t] = v;
  __syncthreads();
  for (int off = 1; off < 256; off <<= 1){
    int u = (t >= off) ? sd[t-off] : 0;
    __syncthreads();
    sd[t] += u;
    __syncthreads();
  }
  if (t < nb) bsum[t] = sd[t] - v;  // exclusive
}
__global__ void k_scan3(const int* __restrict__ deg, const int* __restrict__ boff,
                        int* __restrict__ rowptr, int* __restrict__ cursor, int n){
  __shared__ int sd[256];
  int t = threadIdx.x;
  int i = blockIdx.x*256 + t;
  int v = (i < n) ? deg[i] : 0;
  sd[t] = v;
  __syncthreads();
  for (int off = 1; off < 256; off <<= 1){
    int u = (t >= off) ? sd[t-off] : 0;
    __syncthreads();
    sd[t] += u;
    __syncthreads();
  }
  int excl = sd[t] - v + boff[blockIdx.x];
  if (i < n){
    rowptr[i] = excl; cursor[i] = excl;
    if (i == n-1) rowptr[n] = excl + v;
  }
}
__global__ void k_fill(const int* __restrict__ dst, int* __restrict__ cursor,
                       int* __restrict__ eid, int ne){
  int e = blockIdx.x*blockDim.x + threadIdx.x;
  if (e >= ne) return;
  int pos = atomicAdd(&cursor[dst[e]], 1);
  eid[pos] = e;
}

// ---------------- edge logits (no atomics) ----------------
// GATEConv: lrelu( sum_h lrelu(xW1[s,h]+ea*W1[h,128]) * attl[h] + rdot[d] )
__global__ void k_edge_logit_gate(const float* __restrict__ xW1, const float* __restrict__ gateW1,
                                  const float* __restrict__ attl, const float* __restrict__ rdot,
                                  const float* __restrict__ ea, const int* __restrict__ src,
                                  const int* __restrict__ dst, float* __restrict__ logit, int ne){
  int e = blockIdx.x*4 + (threadIdx.x >> 6);
  int lane = threadIdx.x & 63;
  if (e >= ne) return;
  int s = src[e], d = dst[e];
  float eav = ea[e];
  const float* xr = xW1 + (size_t)s*H;
  float2 xv = *(const float2*)&xr[2*lane];
  float v0 = lrelu(xv.x + eav * gateW1[(2*lane)*129 + 128]);
  float v1 = lrelu(xv.y + eav * gateW1[(2*lane+1)*129 + 128]);
  float p = v0*attl[2*lane] + v1*attl[2*lane+1];
  p = wred(p);
  if (lane == 0) logit[e] = lrelu(p + rdot[d]);
}
// GATConv: lrelu(ssrc[s] + sdst[d])
__global__ void k_edge_logit_gat(const float* __restrict__ ssrc, const float* __restrict__ sdst,
                                 const int* __restrict__ src, const int* __restrict__ dst,
                                 float* __restrict__ logit, int ne){
  int e = blockIdx.x*blockDim.x + threadIdx.x;
  if (e >= ne) return;
  logit[e] = lrelu(ssrc[src[e]] + sdst[dst[e]]);
}

// ---------------- per-node softmax + weighted aggregation ----------------
// one wave per node: m = max logit, s = sum exp, acc = bias + sum_e exp(l-m)/s * val[src[e]]
__global__ void k_node_agg(const int* __restrict__ rowptr, const int* __restrict__ eid,
                           const int* __restrict__ src, const float* __restrict__ logit,
                           const float* __restrict__ val, const float* __restrict__ bias,
                           float* __restrict__ hbuf, int n){
  int i = blockIdx.x*4 + (threadIdx.x >> 6);
  int lane = threadIdx.x & 63;
  if (i >= n) return;
  int b = rowptr[i], e1 = rowptr[i+1];
  float m = -1e30f;
  for (int j = b+lane; j < e1; j += 64) m = fmaxf(m, logit[eid[j]]);
  m = wredmax(m);
  float s = 0.f;
  for (int j = b+lane; j < e1; j += 64) s += expf(logit[eid[j]] - m);
  s = wred(s);
  float inv = (s > 0.f) ? 1.f/s : 0.f;
  float2 acc = make_float2(bias[2*lane], bias[2*lane+1]);
  for (int j = b; j < e1; ++j){
    int e = eid[j];
    float w = expf(logit[e] - m) * inv;
    const float2 v = *(const float2*)&val[(size_t)src[e]*H + 2*lane];
    acc.x += v.x*w; acc.y += v.y*w;
  }
  *(float2*)&hbuf[(size_t)i*H + 2*lane] = acc;
}

// GRUCell combine: x = relu((1-z)*n + z*x)
__global__ void k_gru_combine(const float* __restrict__ gi, const float* __restrict__ gh,
                              const float* __restrict__ bih, const float* __restrict__ bhh,
                              float* __restrict__ x, int n){
  int idx = blockIdx.x*blockDim.x + threadIdx.x;
  if (idx >= n*H) return;
  int i = idx >> 7, t = idx & 127;
  const float* gir = gi + (size_t)i*384;
  const float* ghr = gh + (size_t)i*384;
  float ir = gir[t] + bih[t], iz = gir[t+128] + bih[t+128], in = gir[t+256] + bih[t+256];
  float hr = ghr[t] + bhh[t], hz = ghr[t+128] + bhh[t+128], hn = ghr[t+256] + bhh[t+256];
  float r = sigm(ir + hr), z = sigm(iz + hz);
  float nn = tanhf(in + r*hn);
  float xo = (1.f - z)*nn + z*x[idx];
  x[idx] = fmaxf(xo, 0.f);
}

// ---------------- molecule readout ----------------
__global__ void k_colsum(const float* __restrict__ x, float* __restrict__ outraw,
                         int n, int chunk){
  int t = threadIdx.x; // 128
  int start = blockIdx.x*chunk;
  int end = min(start + chunk, n);
  float s = 0.f;
  for (int i = start; i < end; ++i) s += x[(size_t)i*H + t];
  if (start < end) atomicAdd(&outraw[t], s);
}
__global__ void k_mol_prep(const float* __restrict__ outraw, const float* __restrict__ molW,
                           const float* __restrict__ attdst, float* __restrict__ hidvec,
                           float* __restrict__ cdst){
  __shared__ float hs[128];
  __shared__ float red[128];
  int t = threadIdx.x;
  float hv = fmaxf(outraw[t], 0.f);
  hs[t] = hv; hidvec[t] = hv;
  __syncthreads();
  float o = 0.f;
  for (int k = 0; k < 128; ++k) o += hs[k]*molW[t*128+k];
  red[t] = o * attdst[t];
  __syncthreads();
  for (int s = 64; s > 0; s >>= 1){
    if (t < s) red[t] += red[t+s];
    __syncthreads();
  }
  if (t == 0) cdst[0] = red[0];
}
__global__ void k_mol_logit(float* __restrict__ a, const float* __restrict__ cdst,
                            unsigned* __restrict__ gmax, int n){
  int i = blockIdx.x*blockDim.x + threadIdx.x;
  if (i >= n) return;
  float l = lrelu(a[i] + cdst[0]);
  a[i] = l;
  atomicMax(gmax, fenc(l));
}
__global__ void k_mol_exp(float* __restrict__ a, const unsigned* __restrict__ gmax,
                          float* __restrict__ gsum, int n){
  int i = blockIdx.x*blockDim.x + threadIdx.x;
  int lane = threadIdx.x & 63;
  float gm = fdec(gmax[0]);
  float ex = 0.f;
  if (i < n){ ex = expf(a[i] - gm); a[i] = ex; }
  float s = wred(ex);
  if (lane == 0) atomicAdd(gsum, s);
}
__global__ void k_mol_acc(const float* __restrict__ xs, const float* __restrict__ a,
                          float* __restrict__ num, int n, int chunk){
  int t = threadIdx.x; // 128
  int start = blockIdx.x*chunk;
  int end = min(start + chunk, n);
  float s = 0.f;
  for (int i = start; i < end; ++i) s += xs[(size_t)i*H + t]*a[i];
  if (start < end) atomicAdd(&num[t], s);
}
__global__ void k_mol_final(const float* __restrict__ num, const float* __restrict__ gsum,
                            const float* __restrict__ molb, const float* __restrict__ hidvec,
                            const float* __restrict__ Wih, const float* __restrict__ Whh,
                            const float* __restrict__ bih, const float* __restrict__ bhh,
                            float* __restrict__ out){
  __shared__ float hv[128], hd[128];
  int t = threadIdx.x;
  hv[t] = eluf(num[t]/gsum[0] + molb[t]);
  hd[t] = hidvec[t];
  __syncthreads();
  float gr = bih[t], gz = bih[t+128], gn = bih[t+256];
  float hr = bhh[t], hz = bhh[t+128], hn = bhh[t+256];
  for (int k = 0; k < 128; ++k){
    float h = hv[k], d = hd[k];
    gr += h*Wih[t*128+k];       gz += h*Wih[(t+128)*128+k]; gn += h*Wih[(t+256)*128+k];
    hr += d*Whh[t*128+k];       hz += d*Whh[(t+128)*128+k]; hn += d*Whh[(t+256)*128+k];
  }
  float r = sigm(gr+hr), z = sigm(gz+hz);
  float nn = tanhf(gn + r*hn);
  float o = (1.f-z)*nn + z*hd[t];
  out[t] = fmaxf(o, 0.f);
}

extern "C" void kernel_launch(void* const* d_in, const int* in_sizes, int n_in,
                              void* d_out, int out_size, void* d_ws, size_t ws_size,
                              hipStream_t stream){
  const float* node_attr = (const float*)d_in[0];
  const int*   eidx      = (const int*)d_in[1];
  const float* eattr     = (const float*)d_in[2];
  const float* W_lin1    = (const float*)d_in[3];
  const float* b_lin1    = (const float*)d_in[4];
  const float* gate_W1   = (const float*)d_in[5];
  const float* gate_W2   = (const float*)d_in[6];
  const float* gate_att_l= (const float*)d_in[7];
  const float* gate_att_r= (const float*)d_in[8];
  const float* gate_b    = (const float*)d_in[9];
  const float* g1_Wih    = (const float*)d_in[10];
  const float* g1_Whh    = (const float*)d_in[11];
  const float* g1_bih    = (const float*)d_in[12];
  const float* g1_bhh    = (const float*)d_in[13];
  const float* atom_W    = (const float*)d_in[14];
  const float* atom_as   = (const float*)d_in[15];
  const float* atom_ad   = (const float*)d_in[16];
  const float* atom_b    = (const float*)d_in[17];
  const float* g2_Wih    = (const float*)d_in[18];
  const float* g2_Whh    = (const float*)d_in[19];
  const float* g2_bih    = (const float*)d_in[20];
  const float* g2_bhh    = (const float*)d_in[21];
  const float* mol_W     = (const float*)d_in[22];
  const float* mol_as    = (const float*)d_in[23];
  const float* mol_ad    = (const float*)d_in[24];
  const float* mol_b     = (const float*)d_in[25];
  const float* gm_Wih    = (const float*)d_in[26];
  const float* gm_Whh    = (const float*)d_in[27];
  const float* gm_bih    = (const float*)d_in[28];
  const float* gm_bhh    = (const float*)d_in[29];

  const int n  = in_sizes[0];        // N
  const int ne = in_sizes[1] / 2;    // E
  const int* src = eidx;
  const int* dst = eidx + ne;

  // ---- workspace layout ----
  float* ws = (float*)d_ws;
  const size_t NH = (size_t)n * H;
  float* x    = ws;               // [N,H]
  float* t0   = ws + NH;          // [N,H]  xW1 / xt
  float* t1   = ws + 2*NH;        // [N,H]  xW2 / xs
  float* hbuf = ws + 3*NH;        // [N,H]  aggregation result
  float* gi   = ws + 4*NH;        // [N,384]
  float* gh   = t0;               // [N,384] aliases t0..hbuf (stream-ordered safe)
  float* rdot = ws + 7*NH;        // [N]
  float* ssrc = rdot + n;         // [N]
  float* sdst = ssrc + n;         // [N]
  float* ealpha = sdst + n;       // [E] logits
  int* deg    = (int*)(ealpha + ne);  // [N]
  int* cursor = deg + n;              // [N]
  int* rowptr = cursor + n;           // [N+1]
  int* bsum   = rowptr + n + 1;       // [256]
  int* eid    = bsum + 256;           // [E]
  float* outraw = (float*)(eid + ne); // [128]
  float* hidvec = outraw + 128;
  float* cdstp  = hidvec + 128;       // [1]
  unsigned* gmax = (unsigned*)(cdstp + 1);
  float* gsum   = (float*)gmax + 1;
  float* numv   = gsum + 1;           // [128]

  const int nh_blocks   = (n*H + 255)/256;
  const int gemm_blocks = (n + 31)/32;
  const int nwave4      = (n + 3)/4;
  const int ewave4      = (ne + 3)/4;
  const int ethr        = (ne + 255)/256;
  const int nthr        = (n + 255)/256;
  const int nb          = (n + 255)/256;   // scan blocks (must be <= 256)
  const int chunk       = (n + 255)/256;

  // ---- node init + CSR build (independent streams of work) ----
  k_node_init<<<nh_blocks,256,0,stream>>>(node_attr, W_lin1, b_lin1, x, n);
  hipMemsetAsync(deg, 0, (size_t)n*4, stream);
  k_hist<<<ethr,256,0,stream>>>(dst, deg, ne);
  k_scan1<<<nb,256,0,stream>>>(deg, bsum, n);
  k_scan2<<<1,256,0,stream>>>(bsum, nb);
  k_scan3<<<nb,256,0,stream>>>(deg, bsum, rowptr, cursor, n);
  k_fill<<<ethr,256,0,stream>>>(dst, cursor, eid, ne);

  // ---- GATEConv ----
  k_gemm128<<<gemm_blocks,256,0,stream>>>(x, gate_W1, t0, n, 129, H, 0);   // xW1
  k_gemm128<<<gemm_blocks,256,0,stream>>>(x, gate_W2, t1, n, 128, H, 0);   // xW2
  k_rowdot2<<<nwave4,256,0,stream>>>(x, gate_att_r, nullptr, rdot, nullptr, n);
  k_edge_logit_gate<<<ewave4,256,0,stream>>>(t0, gate_W1, gate_att_l, rdot, eattr,
                                             src, dst, ealpha, ne);
  k_node_agg<<<nwave4,256,0,stream>>>(rowptr, eid, src, ealpha, t1, gate_b, hbuf, n);
  for (int c = 0; c < 3; ++c)
    k_gemm128<<<gemm_blocks,256,0,stream>>>(hbuf, g1_Wih + c*128*128, gi + c*128, n, 128, 384, 1);
  for (int c = 0; c < 3; ++c)
    k_gemm128<<<gemm_blocks,256,0,stream>>>(x, g1_Whh + c*128*128, gh + c*128, n, 128, 384, 0);
  k_gru_combine<<<nh_blocks,256,0,stream>>>(gi, gh, g1_bih, g1_bhh, x, n);

  // ---- GATConv ----
  k_gemm128<<<gemm_blocks,256,0,stream>>>(x, atom_W, t0, n, 128, H, 0);    // xt
  k_rowdot2<<<nwave4,256,0,stream>>>(t0, atom_as, atom_ad, ssrc, sdst, n);
  k_edge_logit_gat<<<ethr,256,0,stream>>>(ssrc, sdst, src, dst, ealpha, ne);
  k_node_agg<<<nwave4,256,0,stream>>>(rowptr, eid, src, ealpha, t0, atom_b, hbuf, n);
  for (int c = 0; c < 3; ++c)
    k_gemm128<<<gemm_blocks,256,0,stream>>>(hbuf, g2_Wih + c*128*128, gi + c*128, n, 128, 384, 1);
  for (int c = 0; c < 3; ++c)
    k_gemm128<<<gemm_blocks,256,0,stream>>>(x, g2_Whh + c*128*128, gh + c*128, n, 128, 384, 0);
  k_gru_combine<<<nh_blocks,256,0,stream>>>(gi, gh, g2_bih, g2_bhh, x, n);

  // ---- molecule readout ----
  hipMemsetAsync(outraw, 0, 128*4, stream);
  hipMemsetAsync(gmax, 0, 4, stream);
  hipMemsetAsync(gsum, 0, 4, stream);
  hipMemsetAsync(numv, 0, 128*4, stream);
  k_colsum<<<256,128,0,stream>>>(x, outraw, n, chunk);
  k_mol_prep<<<1,128,0,stream>>>(outraw, mol_W, mol_ad, hidvec, cdstp);
  k_gemm128<<<gemm_blocks,256,0,stream>>>(x, mol_W, t1, n, 128, H, 0);     // xs
  k_rowdot2<<<nwave4,256,0,stream>>>(t1, mol_as, nullptr, rdot, nullptr, n);
  k_mol_logit<<<nthr,256,0,stream>>>(rdot, cdstp, gmax, n);
  k_mol_exp<<<nthr,256,0,stream>>>(rdot, gmax, gsum, n);
  k_mol_acc<<<256,128,0,stream>>>(t1, rdot, numv, n, chunk);
  k_mol_final<<<1,128,0,stream>>>(numv, gsum, mol_b, hidvec,
                                  gm_Wih, gm_Whh, gm_bih, gm_bhh, (float*)d_out);
}

// Round 3
// 1398.540 us; speedup vs baseline: 1.4647x; 1.1618x over previous
//
#include <hip/hip_runtime.h>
#include <math.h>

#define H 128
#define NEGS 0.01f

__device__ __forceinline__ float lrelu(float x){ return x >= 0.f ? x : NEGS*x; }
__device__ __forceinline__ float eluf(float x){ return x > 0.f ? x : expf(x)-1.f; }
__device__ __forceinline__ float sigm(float x){ return 1.f/(1.f+expf(-x)); }
__device__ __forceinline__ float wred(float v){
  #pragma unroll
  for (int off = 32; off > 0; off >>= 1) v += __shfl_xor(v, off, 64);
  return v;
}
__device__ __forceinline__ float wredmax(float v){
  #pragma unroll
  for (int off = 32; off > 0; off >>= 1) v = fmaxf(v, __shfl_xor(v, off, 64));
  return v;
}
__device__ __forceinline__ unsigned fenc(float f){
  unsigned u = __float_as_uint(f);
  return (u & 0x80000000u) ? ~u : (u | 0x80000000u);
}
__device__ __forceinline__ float fdec(unsigned v){
  return __uint_as_float((v & 0x80000000u) ? (v ^ 0x80000000u) : ~v);
}

// x[i,t] = lrelu(node_attr[i]*W_lin1[t] + b_lin1[t])
__global__ void k_node_init(const float* __restrict__ na, const float* __restrict__ wl,
                            const float* __restrict__ bl, float* __restrict__ x, int n){
  int idx = blockIdx.x*blockDim.x + threadIdx.x;
  if (idx >= n*H) return;
  int i = idx >> 7, t = idx & 127;
  x[idx] = lrelu(na[i]*wl[t] + bl[t]);
}

// Y[i*ldy + m] = sum_k act(X[i*128+k]) * W[m*ldw + k],  m in [0,128)
__global__ __launch_bounds__(256)
void k_gemm128(const float* __restrict__ X, const float* __restrict__ W,
               float* __restrict__ Y, int n, int ldw, int ldy, int elu_in){
  __shared__ float Wt[64*132];   // Wt[k][m], stride 132
  __shared__ float Xs[64*36];    // Xs[k][node], stride 36
  int t = threadIdx.x;
  int i0 = blockIdx.x*32;
  int tm = t & 31, tn = t >> 5;
  float a00=0,a01=0,a02=0,a03=0, a10=0,a11=0,a12=0,a13=0;
  float a20=0,a21=0,a22=0,a23=0, a30=0,a31=0,a32=0,a33=0;
  for (int kc = 0; kc < 128; kc += 64){
    #pragma unroll
    for (int j = 0; j < 32; ++j){
      int idx = j*256 + t;
      int m = idx >> 6, k = idx & 63;
      Wt[k*132 + m] = W[m*ldw + kc + k];
    }
    #pragma unroll
    for (int j = 0; j < 8; ++j){
      int idx = j*256 + t;
      int node = idx >> 6, k = idx & 63;
      int i = i0 + node;
      float v = (i < n) ? X[(size_t)i*H + kc + k] : 0.f;
      if (elu_in) v = eluf(v);
      Xs[k*36 + node] = v;
    }
    __syncthreads();
    #pragma unroll 8
    for (int k = 0; k < 64; ++k){
      const float4 wv = *(const float4*)&Wt[k*132 + tm*4];
      const float4 xv = *(const float4*)&Xs[k*36 + tn*4];
      a00 += wv.x*xv.x; a01 += wv.x*xv.y; a02 += wv.x*xv.z; a03 += wv.x*xv.w;
      a10 += wv.y*xv.x; a11 += wv.y*xv.y; a12 += wv.y*xv.z; a13 += wv.y*xv.w;
      a20 += wv.z*xv.x; a21 += wv.z*xv.y; a22 += wv.z*xv.z; a23 += wv.z*xv.w;
      a30 += wv.w*xv.x; a31 += wv.w*xv.y; a32 += wv.w*xv.z; a33 += wv.w*xv.w;
    }
    __syncthreads();
  }
  float accm[4][4] = {{a00,a01,a02,a03},{a10,a11,a12,a13},{a20,a21,a22,a23},{a30,a31,a32,a33}};
  #pragma unroll
  for (int b = 0; b < 4; ++b){
    int i = i0 + tn*4 + b;
    if (i < n){
      float4 o = make_float4(accm[0][b], accm[1][b], accm[2][b], accm[3][b]);
      *(float4*)&Y[(size_t)i*ldy + tm*4] = o;
    }
  }
}

// 3-chunk GEMM: Y[i*384 + c*128 + m] = sum_k act(X[i,k]) * W[(c*128+m)*128 + k]
// X tile staged once per K-chunk, W chunks looped with resident 48-reg accumulator.
__global__ __launch_bounds__(256)
void k_gemm384(const float* __restrict__ X, const float* __restrict__ W,
               float* __restrict__ Y, int n, int elu_in){
  __shared__ float Wt[64*132];
  __shared__ float Xs[64*36];
  int t = threadIdx.x;
  int i0 = blockIdx.x*32;
  int tm = t & 31, tn = t >> 5;
  float acc[3][16];
  #pragma unroll
  for (int c = 0; c < 3; ++c)
    #pragma unroll
    for (int r = 0; r < 16; ++r) acc[c][r] = 0.f;
  for (int kc = 0; kc < 128; kc += 64){
    __syncthreads();                      // protect Xs/Wt from previous iteration's use
    #pragma unroll
    for (int j = 0; j < 8; ++j){
      int idx = j*256 + t;
      int node = idx >> 6, k = idx & 63;
      int i = i0 + node;
      float v = (i < n) ? X[(size_t)i*H + kc + k] : 0.f;
      if (elu_in) v = eluf(v);
      Xs[k*36 + node] = v;
    }
    #pragma unroll
    for (int c = 0; c < 3; ++c){
      if (c > 0) __syncthreads();         // all done with previous Wt
      #pragma unroll
      for (int j = 0; j < 32; ++j){
        int idx = j*256 + t;
        int m = idx >> 6, k = idx & 63;
        Wt[k*132 + m] = W[(size_t)(c*128 + m)*128 + kc + k];
      }
      __syncthreads();                    // Wt (and Xs on c==0) ready
      #pragma unroll 8
      for (int k = 0; k < 64; ++k){
        const float4 wv = *(const float4*)&Wt[k*132 + tm*4];
        const float4 xv = *(const float4*)&Xs[k*36 + tn*4];
        acc[c][ 0] += wv.x*xv.x; acc[c][ 1] += wv.x*xv.y; acc[c][ 2] += wv.x*xv.z; acc[c][ 3] += wv.x*xv.w;
        acc[c][ 4] += wv.y*xv.x; acc[c][ 5] += wv.y*xv.y; acc[c][ 6] += wv.y*xv.z; acc[c][ 7] += wv.y*xv.w;
        acc[c][ 8] += wv.z*xv.x; acc[c][ 9] += wv.z*xv.y; acc[c][10] += wv.z*xv.z; acc[c][11] += wv.z*xv.w;
        acc[c][12] += wv.w*xv.x; acc[c][13] += wv.w*xv.y; acc[c][14] += wv.w*xv.z; acc[c][15] += wv.w*xv.w;
      }
    }
  }
  #pragma unroll
  for (int c = 0; c < 3; ++c)
    #pragma unroll
    for (int b = 0; b < 4; ++b){
      int i = i0 + tn*4 + b;
      if (i < n){
        float4 o = make_float4(acc[c][0*4+b], acc[c][1*4+b], acc[c][2*4+b], acc[c][3*4+b]);
        *(float4*)&Y[(size_t)i*384 + c*128 + tm*4] = o;
      }
    }
}

// per-node dots with one or two 128-vectors (one wave per node)
__global__ void k_rowdot2(const float* __restrict__ X, const float* __restrict__ v1,
                          const float* __restrict__ v2, float* __restrict__ o1,
                          float* __restrict__ o2, int n){
  int i = blockIdx.x*4 + (threadIdx.x >> 6);
  int lane = threadIdx.x & 63;
  if (i >= n) return;
  const float* xr = X + (size_t)i*H;
  float a = xr[lane]*v1[lane] + xr[lane+64]*v1[lane+64];
  float b = 0.f;
  if (v2) b = xr[lane]*v2[lane] + xr[lane+64]*v2[lane+64];
  a = wred(a);
  if (v2) b = wred(b);
  if (lane == 0){ o1[i] = a; if (v2) o2[i] = b; }
}

// ---------------- CSR build (dst-grouped edge lists) ----------------
__global__ void k_hist(const int* __restrict__ dst, int* __restrict__ deg, int ne){
  int e = blockIdx.x*blockDim.x + threadIdx.x;
  if (e < ne) atomicAdd(&deg[dst[e]], 1);
}
__global__ void k_scan1(const int* __restrict__ deg, int* __restrict__ bsum, int n){
  __shared__ int sd[256];
  int i = blockIdx.x*256 + threadIdx.x;
  sd[threadIdx.x] = (i < n) ? deg[i] : 0;
  __syncthreads();
  for (int s = 128; s > 0; s >>= 1){
    if (threadIdx.x < s) sd[threadIdx.x] += sd[threadIdx.x+s];
    __syncthreads();
  }
  if (threadIdx.x == 0) bsum[blockIdx.x] = sd[0];
}
__global__ void k_scan2(int* __restrict__ bsum, int nb){   // nb <= 256, single block
  __shared__ int sd[256];
  int t = threadIdx.x;
  int v = (t < nb) ? bsum[t] : 0;
  sd[t] = v;
  __syncthreads();
  for (int off = 1; off < 256; off <<= 1){
    int u = (t >= off) ? sd[t-off] : 0;
    __syncthreads();
    sd[t] += u;
    __syncthreads();
  }
  if (t < nb) bsum[t] = sd[t] - v;  // exclusive
}
__global__ void k_scan3(const int* __restrict__ deg, const int* __restrict__ boff,
                        int* __restrict__ rowptr, int* __restrict__ cursor, int n){
  __shared__ int sd[256];
  int t = threadIdx.x;
  int i = blockIdx.x*256 + t;
  int v = (i < n) ? deg[i] : 0;
  sd[t] = v;
  __syncthreads();
  for (int off = 1; off < 256; off <<= 1){
    int u = (t >= off) ? sd[t-off] : 0;
    __syncthreads();
    sd[t] += u;
    __syncthreads();
  }
  int excl = sd[t] - v + boff[blockIdx.x];
  if (i < n){
    rowptr[i] = excl; cursor[i] = excl;
    if (i == n-1) rowptr[n] = excl + v;
  }
}
__global__ void k_fill(const int* __restrict__ dst, int* __restrict__ cursor,
                       int* __restrict__ eid, int ne){
  int e = blockIdx.x*blockDim.x + threadIdx.x;
  if (e >= ne) return;
  int pos = atomicAdd(&cursor[dst[e]], 1);
  eid[pos] = e;
}

// pack[l] = (W1col[2l], W1col[2l+1], attl[2l], attl[2l+1]) — lane-indexed, coalesced
__global__ void k_pack_gate(const float* __restrict__ gateW1, const float* __restrict__ attl,
                            float4* __restrict__ pack){
  int l = threadIdx.x;
  if (l < 64)
    pack[l] = make_float4(gateW1[(2*l)*129 + 128], gateW1[(2*l+1)*129 + 128],
                          attl[2*l], attl[2*l+1]);
}

// GATEConv edge logits: lrelu( sum_h lrelu(xW1[s,h]+ea*W1col[h]) * attl[h] + rdot[d] )
__global__ void k_edge_logit_gate(const float* __restrict__ xW1, const float4* __restrict__ pack,
                                  const float* __restrict__ rdot, const float* __restrict__ ea,
                                  const int* __restrict__ src, const int* __restrict__ dst,
                                  float* __restrict__ logit, int ne){
  int e = blockIdx.x*4 + (threadIdx.x >> 6);
  int lane = threadIdx.x & 63;
  if (e >= ne) return;
  int s = src[e], d = dst[e];
  float eav = ea[e];
  float4 p = pack[lane];                      // w0,w1,a0,a1 (L1-resident, coalesced)
  const float2 xv = *(const float2*)&xW1[(size_t)s*H + 2*lane];
  float acc = lrelu(xv.x + eav*p.x)*p.z + lrelu(xv.y + eav*p.y)*p.w;
  acc = wred(acc);
  if (lane == 0) logit[e] = lrelu(acc + rdot[d]);
}

// ---------------- per-node softmax + weighted aggregation ----------------
// GATE variant: logits precomputed in logit[]
__global__ void k_node_agg(const int* __restrict__ rowptr, const int* __restrict__ eid,
                           const int* __restrict__ src, const float* __restrict__ logit,
                           const float* __restrict__ val, const float* __restrict__ bias,
                           float* __restrict__ hbuf, int n){
  int i = blockIdx.x*4 + (threadIdx.x >> 6);
  int lane = threadIdx.x & 63;
  if (i >= n) return;
  int b = rowptr[i], e1 = rowptr[i+1];
  float m = -1e30f;
  for (int j = b+lane; j < e1; j += 64) m = fmaxf(m, logit[eid[j]]);
  m = wredmax(m);
  float s = 0.f;
  for (int j = b+lane; j < e1; j += 64) s += expf(logit[eid[j]] - m);
  s = wred(s);
  float inv = (s > 0.f) ? 1.f/s : 0.f;
  float2 acc = make_float2(bias[2*lane], bias[2*lane+1]);
  for (int j = b; j < e1; ++j){
    int e = eid[j];
    float w = expf(logit[e] - m) * inv;
    const float2 v = *(const float2*)&val[(size_t)src[e]*H + 2*lane];
    acc.x += v.x*w; acc.y += v.y*w;
  }
  *(float2*)&hbuf[(size_t)i*H + 2*lane] = acc;
}

// GAT variant: logit = lrelu(ssrc[src[e]] + sdst[i]) computed inline
__global__ void k_node_agg_gat(const int* __restrict__ rowptr, const int* __restrict__ eid,
                               const int* __restrict__ src, const float* __restrict__ ssrc,
                               const float* __restrict__ sdst, const float* __restrict__ val,
                               const float* __restrict__ bias, float* __restrict__ hbuf, int n){
  int i = blockIdx.x*4 + (threadIdx.x >> 6);
  int lane = threadIdx.x & 63;
  if (i >= n) return;
  int b = rowptr[i], e1 = rowptr[i+1];
  float sdi = sdst[i];
  float m = -1e30f;
  for (int j = b+lane; j < e1; j += 64) m = fmaxf(m, lrelu(ssrc[src[eid[j]]] + sdi));
  m = wredmax(m);
  float s = 0.f;
  for (int j = b+lane; j < e1; j += 64) s += expf(lrelu(ssrc[src[eid[j]]] + sdi) - m);
  s = wred(s);
  float inv = (s > 0.f) ? 1.f/s : 0.f;
  float2 acc = make_float2(bias[2*lane], bias[2*lane+1]);
  for (int j = b; j < e1; ++j){
    int e = eid[j];
    int sn = src[e];
    float w = expf(lrelu(ssrc[sn] + sdi) - m) * inv;
    const float2 v = *(const float2*)&val[(size_t)sn*H + 2*lane];
    acc.x += v.x*w; acc.y += v.y*w;
  }
  *(float2*)&hbuf[(size_t)i*H + 2*lane] = acc;
}

// GRUCell combine: x = relu((1-z)*n + z*x)
__global__ void k_gru_combine(const float* __restrict__ gi, const float* __restrict__ gh,
                              const float* __restrict__ bih, const float* __restrict__ bhh,
                              float* __restrict__ x, int n){
  int idx = blockIdx.x*blockDim.x + threadIdx.x;
  if (idx >= n*H) return;
  int i = idx >> 7, t = idx & 127;
  const float* gir = gi + (size_t)i*384;
  const float* ghr = gh + (size_t)i*384;
  float ir = gir[t] + bih[t], iz = gir[t+128] + bih[t+128], in = gir[t+256] + bih[t+256];
  float hr = ghr[t] + bhh[t], hz = ghr[t+128] + bhh[t+128], hn = ghr[t+256] + bhh[t+256];
  float r = sigm(ir + hr), z = sigm(iz + hz);
  float nn = tanhf(in + r*hn);
  float xo = (1.f - z)*nn + z*x[idx];
  x[idx] = fmaxf(xo, 0.f);
}

// ---------------- molecule readout ----------------
__global__ void k_colsum(const float* __restrict__ x, float* __restrict__ outraw,
                         int n, int chunk){
  int t = threadIdx.x; // 128
  int start = blockIdx.x*chunk;
  int end = min(start + chunk, n);
  float s = 0.f;
  for (int i = start; i < end; ++i) s += x[(size_t)i*H + t];
  if (start < end) atomicAdd(&outraw[t], s);
}
__global__ void k_mol_prep(const float* __restrict__ outraw, const float* __restrict__ molW,
                           const float* __restrict__ attdst, float* __restrict__ hidvec,
                           float* __restrict__ cdst){
  __shared__ float hs[128];
  __shared__ float red[128];
  int t = threadIdx.x;
  float hv = fmaxf(outraw[t], 0.f);
  hs[t] = hv; hidvec[t] = hv;
  __syncthreads();
  float o = 0.f;
  for (int k = 0; k < 128; ++k) o += hs[k]*molW[t*128+k];
  red[t] = o * attdst[t];
  __syncthreads();
  for (int s = 64; s > 0; s >>= 1){
    if (t < s) red[t] += red[t+s];
    __syncthreads();
  }
  if (t == 0) cdst[0] = red[0];
}
__global__ void k_mol_logit(float* __restrict__ a, const float* __restrict__ cdst,
                            unsigned* __restrict__ gmax, int n){
  int i = blockIdx.x*blockDim.x + threadIdx.x;
  if (i >= n) return;
  float l = lrelu(a[i] + cdst[0]);
  a[i] = l;
  atomicMax(gmax, fenc(l));
}
__global__ void k_mol_exp(float* __restrict__ a, const unsigned* __restrict__ gmax,
                          float* __restrict__ gsum, int n){
  int i = blockIdx.x*blockDim.x + threadIdx.x;
  int lane = threadIdx.x & 63;
  float gm = fdec(gmax[0]);
  float ex = 0.f;
  if (i < n){ ex = expf(a[i] - gm); a[i] = ex; }
  float s = wred(ex);
  if (lane == 0) atomicAdd(gsum, s);
}
__global__ void k_mol_acc(const float* __restrict__ xs, const float* __restrict__ a,
                          float* __restrict__ num, int n, int chunk){
  int t = threadIdx.x; // 128
  int start = blockIdx.x*chunk;
  int end = min(start + chunk, n);
  float s = 0.f;
  for (int i = start; i < end; ++i) s += xs[(size_t)i*H + t]*a[i];
  if (start < end) atomicAdd(&num[t], s);
}
__global__ void k_mol_final(const float* __restrict__ num, const float* __restrict__ gsum,
                            const float* __restrict__ molb, const float* __restrict__ hidvec,
                            const float* __restrict__ Wih, const float* __restrict__ Whh,
                            const float* __restrict__ bih, const float* __restrict__ bhh,
                            float* __restrict__ out){
  __shared__ float hv[128], hd[128];
  int t = threadIdx.x;
  hv[t] = eluf(num[t]/gsum[0] + molb[t]);
  hd[t] = hidvec[t];
  __syncthreads();
  float gr = bih[t], gz = bih[t+128], gn = bih[t+256];
  float hr = bhh[t], hz = bhh[t+128], hn = bhh[t+256];
  for (int k = 0; k < 128; ++k){
    float h = hv[k], d = hd[k];
    gr += h*Wih[t*128+k];       gz += h*Wih[(t+128)*128+k]; gn += h*Wih[(t+256)*128+k];
    hr += d*Whh[t*128+k];       hz += d*Whh[(t+128)*128+k]; hn += d*Whh[(t+256)*128+k];
  }
  float r = sigm(gr+hr), z = sigm(gz+hz);
  float nn = tanhf(gn + r*hn);
  float o = (1.f-z)*nn + z*hd[t];
  out[t] = fmaxf(o, 0.f);
}

extern "C" void kernel_launch(void* const* d_in, const int* in_sizes, int n_in,
                              void* d_out, int out_size, void* d_ws, size_t ws_size,
                              hipStream_t stream){
  const float* node_attr = (const float*)d_in[0];
  const int*   eidx      = (const int*)d_in[1];
  const float* eattr     = (const float*)d_in[2];
  const float* W_lin1    = (const float*)d_in[3];
  const float* b_lin1    = (const float*)d_in[4];
  const float* gate_W1   = (const float*)d_in[5];
  const float* gate_W2   = (const float*)d_in[6];
  const float* gate_att_l= (const float*)d_in[7];
  const float* gate_att_r= (const float*)d_in[8];
  const float* gate_b    = (const float*)d_in[9];
  const float* g1_Wih    = (const float*)d_in[10];
  const float* g1_Whh    = (const float*)d_in[11];
  const float* g1_bih    = (const float*)d_in[12];
  const float* g1_bhh    = (const float*)d_in[13];
  const float* atom_W    = (const float*)d_in[14];
  const float* atom_as   = (const float*)d_in[15];
  const float* atom_ad   = (const float*)d_in[16];
  const float* atom_b    = (const float*)d_in[17];
  const float* g2_Wih    = (const float*)d_in[18];
  const float* g2_Whh    = (const float*)d_in[19];
  const float* g2_bih    = (const float*)d_in[20];
  const float* g2_bhh    = (const float*)d_in[21];
  const float* mol_W     = (const float*)d_in[22];
  const float* mol_as    = (const float*)d_in[23];
  const float* mol_ad    = (const float*)d_in[24];
  const float* mol_b     = (const float*)d_in[25];
  const float* gm_Wih    = (const float*)d_in[26];
  const float* gm_Whh    = (const float*)d_in[27];
  const float* gm_bih    = (const float*)d_in[28];
  const float* gm_bhh    = (const float*)d_in[29];

  const int n  = in_sizes[0];        // N
  const int ne = in_sizes[1] / 2;    // E
  const int* src = eidx;
  const int* dst = eidx + ne;

  // ---- workspace layout ----
  float* ws = (float*)d_ws;
  const size_t NH = (size_t)n * H;
  float* x    = ws;               // [N,H]
  float* t0   = ws + NH;          // [N,H]  xW1 / xt
  float* t1   = ws + 2*NH;        // [N,H]  xW2 / xs
  float* hbuf = ws + 3*NH;        // [N,H]
  float* gi   = ws + 4*NH;        // [N,384]
  float* gh   = t0;               // [N,384] aliases t0..hbuf (stream-ordered safe)
  float* rdot = ws + 7*NH;        // [N]
  float* ssrc = rdot + n;         // [N]
  float* sdst = ssrc + n;         // [N]
  float* ealpha = sdst + n;       // [E]
  int* deg    = (int*)(ealpha + ne);  // [N]
  int* cursor = deg + n;              // [N]
  int* rowptr = cursor + n;           // [N+1]
  int* bsum   = rowptr + n + 1;       // [256]
  int* eid    = bsum + 256;           // [E]
  float* outraw = (float*)(eid + ne); // [128]
  float* hidvec = outraw + 128;
  float* cdstp  = hidvec + 128;       // [1]
  unsigned* gmax = (unsigned*)(cdstp + 1);
  float* gsum   = (float*)gmax + 1;
  float* numv   = gsum + 1;           // [128]
  size_t poff = (size_t)(numv + 128 - ws);
  poff = (poff + 3) & ~(size_t)3;     // 16B align
  float4* pack  = (float4*)(ws + poff);  // [64]

  const int nh_blocks   = (n*H + 255)/256;
  const int gemm_blocks = (n + 31)/32;
  const int nwave4      = (n + 3)/4;
  const int ewave4      = (ne + 3)/4;
  const int ethr        = (ne + 255)/256;
  const int nthr        = (n + 255)/256;
  const int nb          = (n + 255)/256;
  const int chunk       = (n + 255)/256;

  // ---- node init + CSR build ----
  k_node_init<<<nh_blocks,256,0,stream>>>(node_attr, W_lin1, b_lin1, x, n);
  hipMemsetAsync(deg, 0, (size_t)n*4, stream);
  k_hist<<<ethr,256,0,stream>>>(dst, deg, ne);
  k_scan1<<<nb,256,0,stream>>>(deg, bsum, n);
  k_scan2<<<1,256,0,stream>>>(bsum, nb);
  k_scan3<<<nb,256,0,stream>>>(deg, bsum, rowptr, cursor, n);
  k_fill<<<ethr,256,0,stream>>>(dst, cursor, eid, ne);
  k_pack_gate<<<1,64,0,stream>>>(gate_W1, gate_att_l, pack);

  // ---- GATEConv ----
  k_gemm128<<<gemm_blocks,256,0,stream>>>(x, gate_W1, t0, n, 129, H, 0);   // xW1
  k_gemm128<<<gemm_blocks,256,0,stream>>>(x, gate_W2, t1, n, 128, H, 0);   // xW2
  k_rowdot2<<<nwave4,256,0,stream>>>(x, gate_att_r, nullptr, rdot, nullptr, n);
  k_edge_logit_gate<<<ewave4,256,0,stream>>>(t0, pack, rdot, eattr, src, dst, ealpha, ne);
  k_node_agg<<<nwave4,256,0,stream>>>(rowptr, eid, src, ealpha, t1, gate_b, hbuf, n);
  k_gemm384<<<gemm_blocks,256,0,stream>>>(hbuf, g1_Wih, gi, n, 1);
  k_gemm384<<<gemm_blocks,256,0,stream>>>(x,    g1_Whh, gh, n, 0);
  k_gru_combine<<<nh_blocks,256,0,stream>>>(gi, gh, g1_bih, g1_bhh, x, n);

  // ---- GATConv ----
  k_gemm128<<<gemm_blocks,256,0,stream>>>(x, atom_W, t0, n, 128, H, 0);    // xt
  k_rowdot2<<<nwave4,256,0,stream>>>(t0, atom_as, atom_ad, ssrc, sdst, n);
  k_node_agg_gat<<<nwave4,256,0,stream>>>(rowptr, eid, src, ssrc, sdst, t0, atom_b, hbuf, n);
  k_gemm384<<<gemm_blocks,256,0,stream>>>(hbuf, g2_Wih, gi, n, 1);
  k_gemm384<<<gemm_blocks,256,0,stream>>>(x,    g2_Whh, gh, n, 0);
  k_gru_combine<<<nh_blocks,256,0,stream>>>(gi, gh, g2_bih, g2_bhh, x, n);

  // ---- molecule readout ----
  hipMemsetAsync(outraw, 0, 128*4, stream);
  hipMemsetAsync(gmax, 0, 4, stream);
  hipMemsetAsync(gsum, 0, 4, stream);
  hipMemsetAsync(numv, 0, 128*4, stream);
  k_colsum<<<256,128,0,stream>>>(x, outraw, n, chunk);
  k_mol_prep<<<1,128,0,stream>>>(outraw, mol_W, mol_ad, hidvec, cdstp);
  k_gemm128<<<gemm_blocks,256,0,stream>>>(x, mol_W, t1, n, 128, H, 0);     // xs
  k_rowdot2<<<nwave4,256,0,stream>>>(t1, mol_as, nullptr, rdot, nullptr, n);
  k_mol_logit<<<nthr,256,0,stream>>>(rdot, cdstp, gmax, n);
  k_mol_exp<<<nthr,256,0,stream>>>(rdot, gmax, gsum, n);
  k_mol_acc<<<256,128,0,stream>>>(t1, rdot, numv, n, chunk);
  k_mol_final<<<1,128,0,stream>>>(numv, gsum, mol_b, hidvec,
                                  gm_Wih, gm_Whh, gm_bih, gm_bhh, (float*)d_out);
}

// Round 4
// 1277.950 us; speedup vs baseline: 1.6030x; 1.0944x over previous
//
#include <hip/hip_runtime.h>
#include <math.h>

#define H 128
#define NEGS 0.01f

__device__ __forceinline__ float lrelu(float x){ return x >= 0.f ? x : NEGS*x; }
__device__ __forceinline__ float eluf(float x){ return x > 0.f ? x : expf(x)-1.f; }
__device__ __forceinline__ float sigm(float x){ return 1.f/(1.f+expf(-x)); }
__device__ __forceinline__ float wred(float v){
  #pragma unroll
  for (int off = 32; off > 0; off >>= 1) v += __shfl_xor(v, off, 64);
  return v;
}
__device__ __forceinline__ float wredmax(float v){
  #pragma unroll
  for (int off = 32; off > 0; off >>= 1) v = fmaxf(v, __shfl_xor(v, off, 64));
  return v;
}
__device__ __forceinline__ unsigned fenc(float f){
  unsigned u = __float_as_uint(f);
  return (u & 0x80000000u) ? ~u : (u | 0x80000000u);
}
__device__ __forceinline__ float fdec(unsigned v){
  return __uint_as_float((v & 0x80000000u) ? (v ^ 0x80000000u) : ~v);
}

// x[i,t] = lrelu(node_attr[i]*W_lin1[t] + b_lin1[t])
__global__ void k_node_init(const float* __restrict__ na, const float* __restrict__ wl,
                            const float* __restrict__ bl, float* __restrict__ x, int n){
  int idx = blockIdx.x*blockDim.x + threadIdx.x;
  if (idx >= n*H) return;
  int i = idx >> 7, t = idx & 127;
  x[idx] = lrelu(na[i]*wl[t] + bl[t]);
}

// Y[i*ldy + m] = sum_k act(X[i*128+k]) * W[m*ldw + k],  m in [0,128)
__global__ __launch_bounds__(256)
void k_gemm128(const float* __restrict__ X, const float* __restrict__ W,
               float* __restrict__ Y, int n, int ldw, int ldy, int elu_in){
  __shared__ float Wt[64*132];   // Wt[k][m], stride 132
  __shared__ float Xs[64*36];    // Xs[k][node], stride 36
  int t = threadIdx.x;
  int i0 = blockIdx.x*32;
  int tm = t & 31, tn = t >> 5;
  float a00=0,a01=0,a02=0,a03=0, a10=0,a11=0,a12=0,a13=0;
  float a20=0,a21=0,a22=0,a23=0, a30=0,a31=0,a32=0,a33=0;
  for (int kc = 0; kc < 128; kc += 64){
    #pragma unroll
    for (int j = 0; j < 32; ++j){
      int idx = j*256 + t;
      int m = idx >> 6, k = idx & 63;
      Wt[k*132 + m] = W[m*ldw + kc + k];
    }
    #pragma unroll
    for (int j = 0; j < 8; ++j){
      int idx = j*256 + t;
      int node = idx >> 6, k = idx & 63;
      int i = i0 + node;
      float v = (i < n) ? X[(size_t)i*H + kc + k] : 0.f;
      if (elu_in) v = eluf(v);
      Xs[k*36 + node] = v;
    }
    __syncthreads();
    #pragma unroll 8
    for (int k = 0; k < 64; ++k){
      const float4 wv = *(const float4*)&Wt[k*132 + tm*4];
      const float4 xv = *(const float4*)&Xs[k*36 + tn*4];
      a00 += wv.x*xv.x; a01 += wv.x*xv.y; a02 += wv.x*xv.z; a03 += wv.x*xv.w;
      a10 += wv.y*xv.x; a11 += wv.y*xv.y; a12 += wv.y*xv.z; a13 += wv.y*xv.w;
      a20 += wv.z*xv.x; a21 += wv.z*xv.y; a22 += wv.z*xv.z; a23 += wv.z*xv.w;
      a30 += wv.w*xv.x; a31 += wv.w*xv.y; a32 += wv.w*xv.z; a33 += wv.w*xv.w;
    }
    __syncthreads();
  }
  float accm[4][4] = {{a00,a01,a02,a03},{a10,a11,a12,a13},{a20,a21,a22,a23},{a30,a31,a32,a33}};
  #pragma unroll
  for (int b = 0; b < 4; ++b){
    int i = i0 + tn*4 + b;
    if (i < n){
      float4 o = make_float4(accm[0][b], accm[1][b], accm[2][b], accm[3][b]);
      *(float4*)&Y[(size_t)i*ldy + tm*4] = o;
    }
  }
}

// 3-chunk GEMM: Y[i*384 + c*128 + m] = sum_k act(X[i,k]) * W[(c*128+m)*128 + k]
__global__ __launch_bounds__(256)
void k_gemm384(const float* __restrict__ X, const float* __restrict__ W,
               float* __restrict__ Y, int n, int elu_in){
  __shared__ float Wt[64*132];
  __shared__ float Xs[64*36];
  int t = threadIdx.x;
  int i0 = blockIdx.x*32;
  int tm = t & 31, tn = t >> 5;
  float acc[3][16];
  #pragma unroll
  for (int c = 0; c < 3; ++c)
    #pragma unroll
    for (int r = 0; r < 16; ++r) acc[c][r] = 0.f;
  for (int kc = 0; kc < 128; kc += 64){
    __syncthreads();
    #pragma unroll
    for (int j = 0; j < 8; ++j){
      int idx = j*256 + t;
      int node = idx >> 6, k = idx & 63;
      int i = i0 + node;
      float v = (i < n) ? X[(size_t)i*H + kc + k] : 0.f;
      if (elu_in) v = eluf(v);
      Xs[k*36 + node] = v;
    }
    #pragma unroll
    for (int c = 0; c < 3; ++c){
      if (c > 0) __syncthreads();
      #pragma unroll
      for (int j = 0; j < 32; ++j){
        int idx = j*256 + t;
        int m = idx >> 6, k = idx & 63;
        Wt[k*132 + m] = W[(size_t)(c*128 + m)*128 + kc + k];
      }
      __syncthreads();
      #pragma unroll 8
      for (int k = 0; k < 64; ++k){
        const float4 wv = *(const float4*)&Wt[k*132 + tm*4];
        const float4 xv = *(const float4*)&Xs[k*36 + tn*4];
        acc[c][ 0] += wv.x*xv.x; acc[c][ 1] += wv.x*xv.y; acc[c][ 2] += wv.x*xv.z; acc[c][ 3] += wv.x*xv.w;
        acc[c][ 4] += wv.y*xv.x; acc[c][ 5] += wv.y*xv.y; acc[c][ 6] += wv.y*xv.z; acc[c][ 7] += wv.y*xv.w;
        acc[c][ 8] += wv.z*xv.x; acc[c][ 9] += wv.z*xv.y; acc[c][10] += wv.z*xv.z; acc[c][11] += wv.z*xv.w;
        acc[c][12] += wv.w*xv.x; acc[c][13] += wv.w*xv.y; acc[c][14] += wv.w*xv.z; acc[c][15] += wv.w*xv.w;
      }
    }
  }
  #pragma unroll
  for (int c = 0; c < 3; ++c)
    #pragma unroll
    for (int b = 0; b < 4; ++b){
      int i = i0 + tn*4 + b;
      if (i < n){
        float4 o = make_float4(acc[c][0*4+b], acc[c][1*4+b], acc[c][2*4+b], acc[c][3*4+b]);
        *(float4*)&Y[(size_t)i*384 + c*128 + tm*4] = o;
      }
    }
}

// per-node dots with one or two 128-vectors (one wave per node)
__global__ void k_rowdot2(const float* __restrict__ X, const float* __restrict__ v1,
                          const float* __restrict__ v2, float* __restrict__ o1,
                          float* __restrict__ o2, int n){
  int i = blockIdx.x*4 + (threadIdx.x >> 6);
  int lane = threadIdx.x & 63;
  if (i >= n) return;
  const float* xr = X + (size_t)i*H;
  float a = xr[lane]*v1[lane] + xr[lane+64]*v1[lane+64];
  float b = 0.f;
  if (v2) b = xr[lane]*v2[lane] + xr[lane+64]*v2[lane+64];
  a = wred(a);
  if (v2) b = wred(b);
  if (lane == 0){ o1[i] = a; if (v2) o2[i] = b; }
}

// ---------------- CSR build (dst-grouped edge lists) ----------------
__global__ void k_hist(const int* __restrict__ dst, int* __restrict__ deg, int ne){
  int e = blockIdx.x*blockDim.x + threadIdx.x;
  if (e < ne) atomicAdd(&deg[dst[e]], 1);
}
__global__ void k_scan1(const int* __restrict__ deg, int* __restrict__ bsum, int n){
  __shared__ int sd[256];
  int i = blockIdx.x*256 + threadIdx.x;
  sd[threadIdx.x] = (i < n) ? deg[i] : 0;
  __syncthreads();
  for (int s = 128; s > 0; s >>= 1){
    if (threadIdx.x < s) sd[threadIdx.x] += sd[threadIdx.x+s];
    __syncthreads();
  }
  if (threadIdx.x == 0) bsum[blockIdx.x] = sd[0];
}
__global__ void k_scan2(int* __restrict__ bsum, int nb){   // nb <= 256, single block
  __shared__ int sd[256];
  int t = threadIdx.x;
  int v = (t < nb) ? bsum[t] : 0;
  sd[t] = v;
  __syncthreads();
  for (int off = 1; off < 256; off <<= 1){
    int u = (t >= off) ? sd[t-off] : 0;
    __syncthreads();
    sd[t] += u;
    __syncthreads();
  }
  if (t < nb) bsum[t] = sd[t] - v;  // exclusive
}
__global__ void k_scan3(const int* __restrict__ deg, const int* __restrict__ boff,
                        int* __restrict__ rowptr, int* __restrict__ cursor, int n){
  __shared__ int sd[256];
  int t = threadIdx.x;
  int i = blockIdx.x*256 + t;
  int v = (i < n) ? deg[i] : 0;
  sd[t] = v;
  __syncthreads();
  for (int off = 1; off < 256; off <<= 1){
    int u = (t >= off) ? sd[t-off] : 0;
    __syncthreads();
    sd[t] += u;
    __syncthreads();
  }
  int excl = sd[t] - v + boff[blockIdx.x];
  if (i < n){
    rowptr[i] = excl; cursor[i] = excl;
    if (i == n-1) rowptr[n] = excl + v;
  }
}
__global__ void k_fill(const int* __restrict__ dst, int* __restrict__ cursor,
                       int* __restrict__ eid, int ne){
  int e = blockIdx.x*blockDim.x + threadIdx.x;
  if (e >= ne) return;
  int pos = atomicAdd(&cursor[dst[e]], 1);
  eid[pos] = e;
}

// contiguous copy of gate_W1[:,128] (edge-attr column, stride 129 originally)
__global__ void k_pack_gate(const float* __restrict__ gateW1, float* __restrict__ w1col){
  int t = threadIdx.x;
  if (t < H) w1col[t] = gateW1[t*129 + 128];
}

// GATEConv edge logits, 16 lanes per edge (4 edges per wave):
// logit[e] = lrelu( sum_h lrelu(xW1[s,h]+ea*w1col[h]) * attl[h] + rdot[d] )
__global__ __launch_bounds__(256)
void k_edge_logit_gate(const float* __restrict__ xW1, const float* __restrict__ w1col,
                       const float* __restrict__ attl, const float* __restrict__ rdot,
                       const float* __restrict__ ea, const int* __restrict__ src,
                       const int* __restrict__ dst, float* __restrict__ logit, int ne){
  int tid = threadIdx.x;
  int e = blockIdx.x*16 + (tid >> 4);
  int g = tid & 15;
  if (e >= ne) return;
  int s = src[e];
  float eav = ea[e];
  const float* xr = xW1 + (size_t)s*H + g*8;
  float4 x0 = *(const float4*)xr;
  float4 x1 = *(const float4*)(xr + 4);
  float4 w0 = *(const float4*)&w1col[g*8];
  float4 w1 = *(const float4*)&w1col[g*8 + 4];
  float4 a0 = *(const float4*)&attl[g*8];
  float4 a1 = *(const float4*)&attl[g*8 + 4];
  float acc = lrelu(x0.x + eav*w0.x)*a0.x + lrelu(x0.y + eav*w0.y)*a0.y
            + lrelu(x0.z + eav*w0.z)*a0.z + lrelu(x0.w + eav*w0.w)*a0.w
            + lrelu(x1.x + eav*w1.x)*a1.x + lrelu(x1.y + eav*w1.y)*a1.y
            + lrelu(x1.z + eav*w1.z)*a1.z + lrelu(x1.w + eav*w1.w)*a1.w;
  #pragma unroll
  for (int off = 1; off < 16; off <<= 1) acc += __shfl_xor(acc, off, 64);
  if (g == 0) logit[e] = lrelu(acc + rdot[dst[e]]);
}

// ---------------- per-node softmax + weighted aggregation ----------------
// one wave per node; single serial pass fuses exp-sum and weighted accumulation
// (every lane computes the identical scalar sum for free; normalize at the end).
__global__ void k_node_agg(const int* __restrict__ rowptr, const int* __restrict__ eid,
                           const int* __restrict__ src, const float* __restrict__ logit,
                           const float* __restrict__ val, const float* __restrict__ bias,
                           float* __restrict__ hbuf, int n){
  int i = blockIdx.x*4 + (threadIdx.x >> 6);
  int lane = threadIdx.x & 63;
  if (i >= n) return;
  int b = rowptr[i], e1 = rowptr[i+1];
  float m = -1e30f;
  for (int j = b+lane; j < e1; j += 64) m = fmaxf(m, logit[eid[j]]);
  m = wredmax(m);
  float s = 0.f;
  float2 acc = make_float2(0.f, 0.f);
  for (int j = b; j < e1; ++j){
    int e = eid[j];
    float w = expf(logit[e] - m);
    s += w;
    const float2 v = *(const float2*)&val[(size_t)src[e]*H + 2*lane];
    acc.x += v.x*w; acc.y += v.y*w;
  }
  float inv = (s > 0.f) ? 1.f/s : 0.f;
  float2 o = make_float2(bias[2*lane] + acc.x*inv, bias[2*lane+1] + acc.y*inv);
  *(float2*)&hbuf[(size_t)i*H + 2*lane] = o;
}

// GAT variant: logit = lrelu(ssrc[src[e]] + sdst[i]) computed inline
__global__ void k_node_agg_gat(const int* __restrict__ rowptr, const int* __restrict__ eid,
                               const int* __restrict__ src, const float* __restrict__ ssrc,
                               const float* __restrict__ sdst, const float* __restrict__ val,
                               const float* __restrict__ bias, float* __restrict__ hbuf, int n){
  int i = blockIdx.x*4 + (threadIdx.x >> 6);
  int lane = threadIdx.x & 63;
  if (i >= n) return;
  int b = rowptr[i], e1 = rowptr[i+1];
  float sdi = sdst[i];
  float m = -1e30f;
  for (int j = b+lane; j < e1; j += 64) m = fmaxf(m, lrelu(ssrc[src[eid[j]]] + sdi));
  m = wredmax(m);
  float s = 0.f;
  float2 acc = make_float2(0.f, 0.f);
  for (int j = b; j < e1; ++j){
    int sn = src[eid[j]];
    float w = expf(lrelu(ssrc[sn] + sdi) - m);
    s += w;
    const float2 v = *(const float2*)&val[(size_t)sn*H + 2*lane];
    acc.x += v.x*w; acc.y += v.y*w;
  }
  float inv = (s > 0.f) ? 1.f/s : 0.f;
  float2 o = make_float2(bias[2*lane] + acc.x*inv, bias[2*lane+1] + acc.y*inv);
  *(float2*)&hbuf[(size_t)i*H + 2*lane] = o;
}

// GRUCell combine: x = relu((1-z)*n + z*x)
__global__ void k_gru_combine(const float* __restrict__ gi, const float* __restrict__ gh,
                              const float* __restrict__ bih, const float* __restrict__ bhh,
                              float* __restrict__ x, int n){
  int idx = blockIdx.x*blockDim.x + threadIdx.x;
  if (idx >= n*H) return;
  int i = idx >> 7, t = idx & 127;
  const float* gir = gi + (size_t)i*384;
  const float* ghr = gh + (size_t)i*384;
  float ir = gir[t] + bih[t], iz = gir[t+128] + bih[t+128], in = gir[t+256] + bih[t+256];
  float hr = ghr[t] + bhh[t], hz = ghr[t+128] + bhh[t+128], hn = ghr[t+256] + bhh[t+256];
  float r = sigm(ir + hr), z = sigm(iz + hz);
  float nn = tanhf(in + r*hn);
  float xo = (1.f - z)*nn + z*x[idx];
  x[idx] = fmaxf(xo, 0.f);
}

// ---------------- molecule readout ----------------
__global__ void k_colsum(const float* __restrict__ x, float* __restrict__ outraw,
                         int n, int chunk){
  int t = threadIdx.x; // 128
  int start = blockIdx.x*chunk;
  int end = min(start + chunk, n);
  float s = 0.f;
  for (int i = start; i < end; ++i) s += x[(size_t)i*H + t];
  if (start < end) atomicAdd(&outraw[t], s);
}
__global__ void k_mol_prep(const float* __restrict__ outraw, const float* __restrict__ molW,
                           const float* __restrict__ attdst, float* __restrict__ hidvec,
                           float* __restrict__ cdst){
  __shared__ float hs[128];
  __shared__ float red[128];
  int t = threadIdx.x;
  float hv = fmaxf(outraw[t], 0.f);
  hs[t] = hv; hidvec[t] = hv;
  __syncthreads();
  float o = 0.f;
  for (int k = 0; k < 128; ++k) o += hs[k]*molW[t*128+k];
  red[t] = o * attdst[t];
  __syncthreads();
  for (int s = 64; s > 0; s >>= 1){
    if (t < s) red[t] += red[t+s];
    __syncthreads();
  }
  if (t == 0) cdst[0] = red[0];
}
__global__ void k_mol_logit(float* __restrict__ a, const float* __restrict__ cdst,
                            unsigned* __restrict__ gmax, int n){
  int i = blockIdx.x*blockDim.x + threadIdx.x;
  if (i >= n) return;
  float l = lrelu(a[i] + cdst[0]);
  a[i] = l;
  atomicMax(gmax, fenc(l));
}
__global__ void k_mol_exp(float* __restrict__ a, const unsigned* __restrict__ gmax,
                          float* __restrict__ gsum, int n){
  int i = blockIdx.x*blockDim.x + threadIdx.x;
  int lane = threadIdx.x & 63;
  float gm = fdec(gmax[0]);
  float ex = 0.f;
  if (i < n){ ex = expf(a[i] - gm); a[i] = ex; }
  float s = wred(ex);
  if (lane == 0) atomicAdd(gsum, s);
}
__global__ void k_mol_acc(const float* __restrict__ xs, const float* __restrict__ a,
                          float* __restrict__ num, int n, int chunk){
  int t = threadIdx.x; // 128
  int start = blockIdx.x*chunk;
  int end = min(start + chunk, n);
  float s = 0.f;
  for (int i = start; i < end; ++i) s += xs[(size_t)i*H + t]*a[i];
  if (start < end) atomicAdd(&num[t], s);
}
__global__ void k_mol_final(const float* __restrict__ num, const float* __restrict__ gsum,
                            const float* __restrict__ molb, const float* __restrict__ hidvec,
                            const float* __restrict__ Wih, const float* __restrict__ Whh,
                            const float* __restrict__ bih, const float* __restrict__ bhh,
                            float* __restrict__ out){
  __shared__ float hv[128], hd[128];
  int t = threadIdx.x;
  hv[t] = eluf(num[t]/gsum[0] + molb[t]);
  hd[t] = hidvec[t];
  __syncthreads();
  float gr = bih[t], gz = bih[t+128], gn = bih[t+256];
  float hr = bhh[t], hz = bhh[t+128], hn = bhh[t+256];
  for (int k = 0; k < 128; ++k){
    float h = hv[k], d = hd[k];
    gr += h*Wih[t*128+k];       gz += h*Wih[(t+128)*128+k]; gn += h*Wih[(t+256)*128+k];
    hr += d*Whh[t*128+k];       hz += d*Whh[(t+128)*128+k]; hn += d*Whh[(t+256)*128+k];
  }
  float r = sigm(gr+hr), z = sigm(gz+hz);
  float nn = tanhf(gn + r*hn);
  float o = (1.f-z)*nn + z*hd[t];
  out[t] = fmaxf(o, 0.f);
}

extern "C" void kernel_launch(void* const* d_in, const int* in_sizes, int n_in,
                              void* d_out, int out_size, void* d_ws, size_t ws_size,
                              hipStream_t stream){
  const float* node_attr = (const float*)d_in[0];
  const int*   eidx      = (const int*)d_in[1];
  const float* eattr     = (const float*)d_in[2];
  const float* W_lin1    = (const float*)d_in[3];
  const float* b_lin1    = (const float*)d_in[4];
  const float* gate_W1   = (const float*)d_in[5];
  const float* gate_W2   = (const float*)d_in[6];
  const float* gate_att_l= (const float*)d_in[7];
  const float* gate_att_r= (const float*)d_in[8];
  const float* gate_b    = (const float*)d_in[9];
  const float* g1_Wih    = (const float*)d_in[10];
  const float* g1_Whh    = (const float*)d_in[11];
  const float* g1_bih    = (const float*)d_in[12];
  const float* g1_bhh    = (const float*)d_in[13];
  const float* atom_W    = (const float*)d_in[14];
  const float* atom_as   = (const float*)d_in[15];
  const float* atom_ad   = (const float*)d_in[16];
  const float* atom_b    = (const float*)d_in[17];
  const float* g2_Wih    = (const float*)d_in[18];
  const float* g2_Whh    = (const float*)d_in[19];
  const float* g2_bih    = (const float*)d_in[20];
  const float* g2_bhh    = (const float*)d_in[21];
  const float* mol_W     = (const float*)d_in[22];
  const float* mol_as    = (const float*)d_in[23];
  const float* mol_ad    = (const float*)d_in[24];
  const float* mol_b     = (const float*)d_in[25];
  const float* gm_Wih    = (const float*)d_in[26];
  const float* gm_Whh    = (const float*)d_in[27];
  const float* gm_bih    = (const float*)d_in[28];
  const float* gm_bhh    = (const float*)d_in[29];

  const int n  = in_sizes[0];        // N
  const int ne = in_sizes[1] / 2;    // E
  const int* src = eidx;
  const int* dst = eidx + ne;

  // ---- workspace layout ----
  float* ws = (float*)d_ws;
  const size_t NH = (size_t)n * H;
  float* x    = ws;               // [N,H]
  float* t0   = ws + NH;          // [N,H]  xW1 / xt
  float* t1   = ws + 2*NH;        // [N,H]  xW2 / xs
  float* hbuf = ws + 3*NH;        // [N,H]
  float* gi   = ws + 4*NH;        // [N,384]
  float* gh   = t0;               // [N,384] aliases t0..hbuf (stream-ordered safe)
  float* rdot = ws + 7*NH;        // [N]
  float* ssrc = rdot + n;         // [N]
  float* sdst = ssrc + n;         // [N]
  float* ealpha = sdst + n;       // [E]
  int* deg    = (int*)(ealpha + ne);  // [N]
  int* cursor = deg + n;              // [N]
  int* rowptr = cursor + n;           // [N+1]
  int* bsum   = rowptr + n + 1;       // [256]
  int* eid    = bsum + 256;           // [E]
  float* outraw = (float*)(eid + ne); // [128]
  float* hidvec = outraw + 128;
  float* cdstp  = hidvec + 128;       // [1]
  unsigned* gmax = (unsigned*)(cdstp + 1);
  float* gsum   = (float*)gmax + 1;
  float* numv   = gsum + 1;           // [128]
  size_t poff = (size_t)(numv + 128 - ws);
  poff = (poff + 3) & ~(size_t)3;     // 16B align
  float* w1col  = ws + poff;          // [128]

  const int nh_blocks   = (n*H + 255)/256;
  const int gemm_blocks = (n + 31)/32;
  const int nwave4      = (n + 3)/4;
  const int e16_blocks  = (ne + 15)/16;
  const int ethr        = (ne + 255)/256;
  const int nthr        = (n + 255)/256;
  const int nb          = (n + 255)/256;
  const int chunk       = (n + 255)/256;

  // ---- node init + CSR build ----
  k_node_init<<<nh_blocks,256,0,stream>>>(node_attr, W_lin1, b_lin1, x, n);
  hipMemsetAsync(deg, 0, (size_t)n*4, stream);
  k_hist<<<ethr,256,0,stream>>>(dst, deg, ne);
  k_scan1<<<nb,256,0,stream>>>(deg, bsum, n);
  k_scan2<<<1,256,0,stream>>>(bsum, nb);
  k_scan3<<<nb,256,0,stream>>>(deg, bsum, rowptr, cursor, n);
  k_fill<<<ethr,256,0,stream>>>(dst, cursor, eid, ne);
  k_pack_gate<<<1,128,0,stream>>>(gate_W1, w1col);

  // ---- GATEConv ----
  k_gemm128<<<gemm_blocks,256,0,stream>>>(x, gate_W1, t0, n, 129, H, 0);   // xW1
  k_gemm128<<<gemm_blocks,256,0,stream>>>(x, gate_W2, t1, n, 128, H, 0);   // xW2
  k_rowdot2<<<nwave4,256,0,stream>>>(x, gate_att_r, nullptr, rdot, nullptr, n);
  k_edge_logit_gate<<<e16_blocks,256,0,stream>>>(t0, w1col, gate_att_l, rdot, eattr,
                                                 src, dst, ealpha, ne);
  k_node_agg<<<nwave4,256,0,stream>>>(rowptr, eid, src, ealpha, t1, gate_b, hbuf, n);
  k_gemm384<<<gemm_blocks,256,0,stream>>>(hbuf, g1_Wih, gi, n, 1);
  k_gemm384<<<gemm_blocks,256,0,stream>>>(x,    g1_Whh, gh, n, 0);
  k_gru_combine<<<nh_blocks,256,0,stream>>>(gi, gh, g1_bih, g1_bhh, x, n);

  // ---- GATConv ----
  k_gemm128<<<gemm_blocks,256,0,stream>>>(x, atom_W, t0, n, 128, H, 0);    // xt
  k_rowdot2<<<nwave4,256,0,stream>>>(t0, atom_as, atom_ad, ssrc, sdst, n);
  k_node_agg_gat<<<nwave4,256,0,stream>>>(rowptr, eid, src, ssrc, sdst, t0, atom_b, hbuf, n);
  k_gemm384<<<gemm_blocks,256,0,stream>>>(hbuf, g2_Wih, gi, n, 1);
  k_gemm384<<<gemm_blocks,256,0,stream>>>(x,    g2_Whh, gh, n, 0);
  k_gru_combine<<<nh_blocks,256,0,stream>>>(gi, gh, g2_bih, g2_bhh, x, n);

  // ---- molecule readout ----
  hipMemsetAsync(outraw, 0, 128*4, stream);
  hipMemsetAsync(gmax, 0, 4, stream);
  hipMemsetAsync(gsum, 0, 4, stream);
  hipMemsetAsync(numv, 0, 128*4, stream);
  k_colsum<<<256,128,0,stream>>>(x, outraw, n, chunk);
  k_mol_prep<<<1,128,0,stream>>>(outraw, mol_W, mol_ad, hidvec, cdstp);
  k_gemm128<<<gemm_blocks,256,0,stream>>>(x, mol_W, t1, n, 128, H, 0);     // xs
  k_rowdot2<<<nwave4,256,0,stream>>>(t1, mol_as, nullptr, rdot, nullptr, n);
  k_mol_logit<<<nthr,256,0,stream>>>(rdot, cdstp, gmax, n);
  k_mol_exp<<<nthr,256,0,stream>>>(rdot, gmax, gsum, n);
  k_mol_acc<<<256,128,0,stream>>>(t1, rdot, numv, n, chunk);
  k_mol_final<<<1,128,0,stream>>>(numv, gsum, mol_b, hidvec,
                                  gm_Wih, gm_Whh, gm_bih, gm_bhh, (float*)d_out);
}

// Round 5
// 801.192 us; speedup vs baseline: 2.5568x; 1.5951x over previous
//
#include <hip/hip_runtime.h>
#include <math.h>

#define H 128
#define NEGS 0.01f

typedef __attribute__((ext_vector_type(8))) short short8;
typedef __attribute__((ext_vector_type(4))) float f32x4;

__device__ __forceinline__ float lrelu(float x){ return x >= 0.f ? x : NEGS*x; }
__device__ __forceinline__ float eluf(float x){ return x > 0.f ? x : expf(x)-1.f; }
__device__ __forceinline__ float sigm(float x){ return 1.f/(1.f+expf(-x)); }
__device__ __forceinline__ float wred(float v){
  #pragma unroll
  for (int off = 32; off > 0; off >>= 1) v += __shfl_xor(v, off, 64);
  return v;
}
__device__ __forceinline__ float wredmax(float v){
  #pragma unroll
  for (int off = 32; off > 0; off >>= 1) v = fmaxf(v, __shfl_xor(v, off, 64));
  return v;
}
__device__ __forceinline__ unsigned fenc(float f){
  unsigned u = __float_as_uint(f);
  return (u & 0x80000000u) ? ~u : (u | 0x80000000u);
}
__device__ __forceinline__ float fdec(unsigned v){
  return __uint_as_float((v & 0x80000000u) ? (v ^ 0x80000000u) : ~v);
}
// bf16 <-> f32 (RNE)
__device__ __forceinline__ unsigned short f2bf(float f){
  unsigned u = __float_as_uint(f);
  u += 0x7fffu + ((u >> 16) & 1u);
  return (unsigned short)(u >> 16);
}
__device__ __forceinline__ float bf2f(unsigned short h){
  return __uint_as_float(((unsigned)h) << 16);
}

// generic weight cast: dst[r*128+c] = bf16(src[r*ld+c]), cols fixed 128
__global__ void k_castw(const float* __restrict__ src, unsigned short* __restrict__ dst,
                        int rows, int ld){
  int idx = blockIdx.x*256 + threadIdx.x;
  if (idx >= rows*H) return;
  int r = idx >> 7, c = idx & 127;
  dst[idx] = f2bf(src[r*ld + c]);
}

// x[i,t] = lrelu(node_attr[i]*W_lin1[t] + b_lin1[t])  (bf16 out)
__global__ void k_node_init(const float* __restrict__ na, const float* __restrict__ wl,
                            const float* __restrict__ bl, unsigned short* __restrict__ x, int n){
  int idx = blockIdx.x*blockDim.x + threadIdx.x;
  if (idx >= n*H) return;
  int i = idx >> 7, t = idx & 127;
  x[idx] = f2bf(lrelu(na[i]*wl[t] + bl[t]));
}

// MFMA GEMM: Y[i*ldy + mbase + m] = sum_k X[i,k]*W[mbase+m,k]; all bf16, f32 accum.
// grid.x = ceil(n/64), grid.y = M/128. block 256 = 4 waves, 16 nodes/wave.
__global__ __launch_bounds__(256)
void k_gemm_mfma(const unsigned short* __restrict__ X, const unsigned short* __restrict__ Wbf,
                 unsigned short* __restrict__ Y, int n, int ldy){
  int w = threadIdx.x >> 6;
  int l = threadIdx.x & 63;
  int i0 = blockIdx.x*64 + w*16;
  int mbase = blockIdx.y*128;
  int row = l & 15;      // node-in-tile for A, col-in-tile for B/D
  int kg  = l >> 4;      // k-group
  f32x4 acc[8];
  #pragma unroll
  for (int c = 0; c < 8; ++c) acc[c] = (f32x4){0.f,0.f,0.f,0.f};
  int ai = i0 + row;
  bool av = (ai < n);
  #pragma unroll
  for (int ks = 0; ks < 4; ++ks){
    int koff = ks*32 + kg*8;
    short8 a = av ? *(const short8*)&X[(size_t)ai*H + koff]
                  : (short8){0,0,0,0,0,0,0,0};
    #pragma unroll
    for (int c = 0; c < 8; ++c){
      short8 b = *(const short8*)&Wbf[(size_t)(mbase + c*16 + row)*H + koff];
      acc[c] = __builtin_amdgcn_mfma_f32_16x16x32_bf16(a, b, acc[c], 0, 0, 0);
    }
  }
  #pragma unroll
  for (int c = 0; c < 8; ++c){
    #pragma unroll
    for (int r = 0; r < 4; ++r){
      int i = i0 + kg*4 + r;
      if (i < n) Y[(size_t)i*ldy + mbase + c*16 + row] = f2bf(acc[c][r]);
    }
  }
}

// per-node dots with one or two 128-vectors (one wave per node), bf16 X
__global__ void k_rowdot2(const unsigned short* __restrict__ X, const float* __restrict__ v1,
                          const float* __restrict__ v2, float* __restrict__ o1,
                          float* __restrict__ o2, int n){
  int i = blockIdx.x*4 + (threadIdx.x >> 6);
  int lane = threadIdx.x & 63;
  if (i >= n) return;
  ushort2 u = *(const ushort2*)&X[(size_t)i*H + 2*lane];
  float x0 = bf2f(u.x), x1 = bf2f(u.y);
  float2 va = *(const float2*)&v1[2*lane];
  float a = x0*va.x + x1*va.y;
  float b = 0.f;
  if (v2){ float2 vb = *(const float2*)&v2[2*lane]; b = x0*vb.x + x1*vb.y; }
  a = wred(a);
  if (v2) b = wred(b);
  if (lane == 0){ o1[i] = a; if (v2) o2[i] = b; }
}

// ---------------- CSR build ----------------
__global__ void k_hist(const int* __restrict__ dst, int* __restrict__ deg, int ne){
  int e = blockIdx.x*blockDim.x + threadIdx.x;
  if (e < ne) atomicAdd(&deg[dst[e]], 1);
}
__global__ void k_scan1(const int* __restrict__ deg, int* __restrict__ bsum, int n){
  __shared__ int sd[256];
  int i = blockIdx.x*256 + threadIdx.x;
  sd[threadIdx.x] = (i < n) ? deg[i] : 0;
  __syncthreads();
  for (int s = 128; s > 0; s >>= 1){
    if (threadIdx.x < s) sd[threadIdx.x] += sd[threadIdx.x+s];
    __syncthreads();
  }
  if (threadIdx.x == 0) bsum[blockIdx.x] = sd[0];
}
__global__ void k_scan2(int* __restrict__ bsum, int nb){
  __shared__ int sd[256];
  int t = threadIdx.x;
  int v = (t < nb) ? bsum[t] : 0;
  sd[t] = v;
  __syncthreads();
  for (int off = 1; off < 256; off <<= 1){
    int u = (t >= off) ? sd[t-off] : 0;
    __syncthreads();
    sd[t] += u;
    __syncthreads();
  }
  if (t < nb) bsum[t] = sd[t] - v;
}
__global__ void k_scan3(const int* __restrict__ deg, const int* __restrict__ boff,
                        int* __restrict__ rowptr, int* __restrict__ cursor, int n){
  __shared__ int sd[256];
  int t = threadIdx.x;
  int i = blockIdx.x*256 + t;
  int v = (i < n) ? deg[i] : 0;
  sd[t] = v;
  __syncthreads();
  for (int off = 1; off < 256; off <<= 1){
    int u = (t >= off) ? sd[t-off] : 0;
    __syncthreads();
    sd[t] += u;
    __syncthreads();
  }
  int excl = sd[t] - v + boff[blockIdx.x];
  if (i < n){
    rowptr[i] = excl; cursor[i] = excl;
    if (i == n-1) rowptr[n] = excl + v;
  }
}
__global__ void k_fill(const int* __restrict__ dst, int* __restrict__ cursor,
                       int* __restrict__ eid, int ne){
  int e = blockIdx.x*blockDim.x + threadIdx.x;
  if (e >= ne) return;
  int pos = atomicAdd(&cursor[dst[e]], 1);
  eid[pos] = e;
}

// contiguous copy of gate_W1[:,128]
__global__ void k_pack_gate(const float* __restrict__ gateW1, float* __restrict__ w1col){
  int t = threadIdx.x;
  if (t < H) w1col[t] = gateW1[t*129 + 128];
}

// GATEConv edge logits, 16 lanes/edge, bf16 xW1
__global__ __launch_bounds__(256)
void k_edge_logit_gate(const unsigned short* __restrict__ xW1, const float* __restrict__ w1col,
                       const float* __restrict__ attl, const float* __restrict__ rdot,
                       const float* __restrict__ ea, const int* __restrict__ src,
                       const int* __restrict__ dst, float* __restrict__ logit, int ne){
  int tid = threadIdx.x;
  int e = blockIdx.x*16 + (tid >> 4);
  int g = tid & 15;
  if (e >= ne) return;
  int s = src[e];
  float eav = ea[e];
  short8 raw = *(const short8*)&xW1[(size_t)s*H + g*8];
  float4 w0 = *(const float4*)&w1col[g*8];
  float4 w1 = *(const float4*)&w1col[g*8 + 4];
  float4 a0 = *(const float4*)&attl[g*8];
  float4 a1 = *(const float4*)&attl[g*8 + 4];
  float acc = lrelu(bf2f((unsigned short)raw[0]) + eav*w0.x)*a0.x
            + lrelu(bf2f((unsigned short)raw[1]) + eav*w0.y)*a0.y
            + lrelu(bf2f((unsigned short)raw[2]) + eav*w0.z)*a0.z
            + lrelu(bf2f((unsigned short)raw[3]) + eav*w0.w)*a0.w
            + lrelu(bf2f((unsigned short)raw[4]) + eav*w1.x)*a1.x
            + lrelu(bf2f((unsigned short)raw[5]) + eav*w1.y)*a1.y
            + lrelu(bf2f((unsigned short)raw[6]) + eav*w1.z)*a1.z
            + lrelu(bf2f((unsigned short)raw[7]) + eav*w1.w)*a1.w;
  #pragma unroll
  for (int off = 1; off < 16; off <<= 1) acc += __shfl_xor(acc, off, 64);
  if (g == 0) logit[e] = lrelu(acc + rdot[dst[e]]);
}

// ---------------- per-node softmax + aggregation (bf16 val, elu fused out) ----------------
__global__ void k_node_agg(const int* __restrict__ rowptr, const int* __restrict__ eid,
                           const int* __restrict__ src, const float* __restrict__ logit,
                           const unsigned short* __restrict__ val, const float* __restrict__ bias,
                           unsigned short* __restrict__ hbuf, int n){
  int i = blockIdx.x*4 + (threadIdx.x >> 6);
  int lane = threadIdx.x & 63;
  if (i >= n) return;
  int b = rowptr[i], e1 = rowptr[i+1];
  float m = -1e30f;
  for (int j = b+lane; j < e1; j += 64) m = fmaxf(m, logit[eid[j]]);
  m = wredmax(m);
  float s = 0.f, ax = 0.f, ay = 0.f;
  int j = b;
  for (; j+4 <= e1; j += 4){
    int e0 = eid[j], e1i = eid[j+1], e2 = eid[j+2], e3 = eid[j+3];
    int s0 = src[e0], s1 = src[e1i], s2 = src[e2], s3 = src[e3];
    float w0 = expf(logit[e0]-m), w1 = expf(logit[e1i]-m);
    float w2 = expf(logit[e2]-m), w3 = expf(logit[e3]-m);
    ushort2 v0 = *(const ushort2*)&val[(size_t)s0*H + 2*lane];
    ushort2 v1 = *(const ushort2*)&val[(size_t)s1*H + 2*lane];
    ushort2 v2 = *(const ushort2*)&val[(size_t)s2*H + 2*lane];
    ushort2 v3 = *(const ushort2*)&val[(size_t)s3*H + 2*lane];
    s += w0+w1+w2+w3;
    ax += bf2f(v0.x)*w0 + bf2f(v1.x)*w1 + bf2f(v2.x)*w2 + bf2f(v3.x)*w3;
    ay += bf2f(v0.y)*w0 + bf2f(v1.y)*w1 + bf2f(v2.y)*w2 + bf2f(v3.y)*w3;
  }
  for (; j < e1; ++j){
    int e = eid[j]; int sn = src[e];
    float w = expf(logit[e]-m);
    ushort2 v = *(const ushort2*)&val[(size_t)sn*H + 2*lane];
    s += w; ax += bf2f(v.x)*w; ay += bf2f(v.y)*w;
  }
  float inv = (s > 0.f) ? 1.f/s : 0.f;
  ushort2 o;
  o.x = f2bf(eluf(bias[2*lane]   + ax*inv));
  o.y = f2bf(eluf(bias[2*lane+1] + ay*inv));
  *(ushort2*)&hbuf[(size_t)i*H + 2*lane] = o;
}

// GAT variant: logit = lrelu(ssrc[src]+sdst[i]) inline
__global__ void k_node_agg_gat(const int* __restrict__ rowptr, const int* __restrict__ eid,
                               const int* __restrict__ src, const float* __restrict__ ssrc,
                               const float* __restrict__ sdst, const unsigned short* __restrict__ val,
                               const float* __restrict__ bias, unsigned short* __restrict__ hbuf, int n){
  int i = blockIdx.x*4 + (threadIdx.x >> 6);
  int lane = threadIdx.x & 63;
  if (i >= n) return;
  int b = rowptr[i], e1 = rowptr[i+1];
  float sdi = sdst[i];
  float m = -1e30f;
  for (int j = b+lane; j < e1; j += 64) m = fmaxf(m, lrelu(ssrc[src[eid[j]]] + sdi));
  m = wredmax(m);
  float s = 0.f, ax = 0.f, ay = 0.f;
  int j = b;
  for (; j+4 <= e1; j += 4){
    int s0 = src[eid[j]], s1 = src[eid[j+1]], s2 = src[eid[j+2]], s3 = src[eid[j+3]];
    float w0 = expf(lrelu(ssrc[s0]+sdi)-m), w1 = expf(lrelu(ssrc[s1]+sdi)-m);
    float w2 = expf(lrelu(ssrc[s2]+sdi)-m), w3 = expf(lrelu(ssrc[s3]+sdi)-m);
    ushort2 v0 = *(const ushort2*)&val[(size_t)s0*H + 2*lane];
    ushort2 v1 = *(const ushort2*)&val[(size_t)s1*H + 2*lane];
    ushort2 v2 = *(const ushort2*)&val[(size_t)s2*H + 2*lane];
    ushort2 v3 = *(const ushort2*)&val[(size_t)s3*H + 2*lane];
    s += w0+w1+w2+w3;
    ax += bf2f(v0.x)*w0 + bf2f(v1.x)*w1 + bf2f(v2.x)*w2 + bf2f(v3.x)*w3;
    ay += bf2f(v0.y)*w0 + bf2f(v1.y)*w1 + bf2f(v2.y)*w2 + bf2f(v3.y)*w3;
  }
  for (; j < e1; ++j){
    int sn = src[eid[j]];
    float w = expf(lrelu(ssrc[sn]+sdi)-m);
    ushort2 v = *(const ushort2*)&val[(size_t)sn*H + 2*lane];
    s += w; ax += bf2f(v.x)*w; ay += bf2f(v.y)*w;
  }
  float inv = (s > 0.f) ? 1.f/s : 0.f;
  ushort2 o;
  o.x = f2bf(eluf(bias[2*lane]   + ax*inv));
  o.y = f2bf(eluf(bias[2*lane+1] + ay*inv));
  *(ushort2*)&hbuf[(size_t)i*H + 2*lane] = o;
}

// GRUCell combine (bf16 gi/gh/x): x = relu((1-z)*n + z*x)
__global__ void k_gru_combine(const unsigned short* __restrict__ gi, const unsigned short* __restrict__ gh,
                              const float* __restrict__ bih, const float* __restrict__ bhh,
                              unsigned short* __restrict__ x, int n){
  int idx = blockIdx.x*blockDim.x + threadIdx.x;
  if (idx >= n*H) return;
  int i = idx >> 7, t = idx & 127;
  const unsigned short* gir = gi + (size_t)i*384;
  const unsigned short* ghr = gh + (size_t)i*384;
  float ir = bf2f(gir[t]) + bih[t], iz = bf2f(gir[t+128]) + bih[t+128], in = bf2f(gir[t+256]) + bih[t+256];
  float hr = bf2f(ghr[t]) + bhh[t], hz = bf2f(ghr[t+128]) + bhh[t+128], hn = bf2f(ghr[t+256]) + bhh[t+256];
  float r = sigm(ir + hr), z = sigm(iz + hz);
  float nn = tanhf(in + r*hn);
  float xo = (1.f - z)*nn + z*bf2f(x[idx]);
  x[idx] = f2bf(fmaxf(xo, 0.f));
}

// ---------------- molecule readout ----------------
__global__ void k_colsum(const unsigned short* __restrict__ x, float* __restrict__ outraw,
                         int n, int chunk){
  int t = threadIdx.x; // 128
  int start = blockIdx.x*chunk;
  int end = min(start + chunk, n);
  float s = 0.f;
  for (int i = start; i < end; ++i) s += bf2f(x[(size_t)i*H + t]);
  if (start < end) atomicAdd(&outraw[t], s);
}
__global__ void k_mol_prep(const float* __restrict__ outraw, const float* __restrict__ molW,
                           const float* __restrict__ attdst, float* __restrict__ hidvec,
                           float* __restrict__ cdst){
  __shared__ float hs[128];
  __shared__ float red[128];
  int t = threadIdx.x;
  float hv = fmaxf(outraw[t], 0.f);
  hs[t] = hv; hidvec[t] = hv;
  __syncthreads();
  float o = 0.f;
  for (int k = 0; k < 128; ++k) o += hs[k]*molW[t*128+k];
  red[t] = o * attdst[t];
  __syncthreads();
  for (int s = 64; s > 0; s >>= 1){
    if (t < s) red[t] += red[t+s];
    __syncthreads();
  }
  if (t == 0) cdst[0] = red[0];
}
__global__ void k_mol_logit(float* __restrict__ a, const float* __restrict__ cdst,
                            unsigned* __restrict__ gmax, int n){
  int i = blockIdx.x*blockDim.x + threadIdx.x;
  if (i >= n) return;
  float l = lrelu(a[i] + cdst[0]);
  a[i] = l;
  atomicMax(gmax, fenc(l));
}
__global__ void k_mol_exp(float* __restrict__ a, const unsigned* __restrict__ gmax,
                          float* __restrict__ gsum, int n){
  int i = blockIdx.x*blockDim.x + threadIdx.x;
  int lane = threadIdx.x & 63;
  float gm = fdec(gmax[0]);
  float ex = 0.f;
  if (i < n){ ex = expf(a[i] - gm); a[i] = ex; }
  float s = wred(ex);
  if (lane == 0) atomicAdd(gsum, s);
}
__global__ void k_mol_acc(const unsigned short* __restrict__ xs, const float* __restrict__ a,
                          float* __restrict__ num, int n, int chunk){
  int t = threadIdx.x; // 128
  int start = blockIdx.x*chunk;
  int end = min(start + chunk, n);
  float s = 0.f;
  for (int i = start; i < end; ++i) s += bf2f(xs[(size_t)i*H + t])*a[i];
  if (start < end) atomicAdd(&num[t], s);
}
__global__ void k_mol_final(const float* __restrict__ num, const float* __restrict__ gsum,
                            const float* __restrict__ molb, const float* __restrict__ hidvec,
                            const float* __restrict__ Wih, const float* __restrict__ Whh,
                            const float* __restrict__ bih, const float* __restrict__ bhh,
                            float* __restrict__ out){
  __shared__ float hv[128], hd[128];
  int t = threadIdx.x;
  hv[t] = eluf(num[t]/gsum[0] + molb[t]);
  hd[t] = hidvec[t];
  __syncthreads();
  float gr = bih[t], gz = bih[t+128], gn = bih[t+256];
  float hr = bhh[t], hz = bhh[t+128], hn = bhh[t+256];
  for (int k = 0; k < 128; ++k){
    float h = hv[k], d = hd[k];
    gr += h*Wih[t*128+k];       gz += h*Wih[(t+128)*128+k]; gn += h*Wih[(t+256)*128+k];
    hr += d*Whh[t*128+k];       hz += d*Whh[(t+128)*128+k]; hn += d*Whh[(t+256)*128+k];
  }
  float r = sigm(gr+hr), z = sigm(gz+hz);
  float nn = tanhf(gn + r*hn);
  float o = (1.f-z)*nn + z*hd[t];
  out[t] = fmaxf(o, 0.f);
}

extern "C" void kernel_launch(void* const* d_in, const int* in_sizes, int n_in,
                              void* d_out, int out_size, void* d_ws, size_t ws_size,
                              hipStream_t stream){
  const float* node_attr = (const float*)d_in[0];
  const int*   eidx      = (const int*)d_in[1];
  const float* eattr     = (const float*)d_in[2];
  const float* W_lin1    = (const float*)d_in[3];
  const float* b_lin1    = (const float*)d_in[4];
  const float* gate_W1   = (const float*)d_in[5];
  const float* gate_W2   = (const float*)d_in[6];
  const float* gate_att_l= (const float*)d_in[7];
  const float* gate_att_r= (const float*)d_in[8];
  const float* gate_b    = (const float*)d_in[9];
  const float* g1_Wih    = (const float*)d_in[10];
  const float* g1_Whh    = (const float*)d_in[11];
  const float* g1_bih    = (const float*)d_in[12];
  const float* g1_bhh    = (const float*)d_in[13];
  const float* atom_W    = (const float*)d_in[14];
  const float* atom_as   = (const float*)d_in[15];
  const float* atom_ad   = (const float*)d_in[16];
  const float* atom_b    = (const float*)d_in[17];
  const float* g2_Wih    = (const float*)d_in[18];
  const float* g2_Whh    = (const float*)d_in[19];
  const float* g2_bih    = (const float*)d_in[20];
  const float* g2_bhh    = (const float*)d_in[21];
  const float* mol_W     = (const float*)d_in[22];
  const float* mol_as    = (const float*)d_in[23];
  const float* mol_ad    = (const float*)d_in[24];
  const float* mol_b     = (const float*)d_in[25];
  const float* gm_Wih    = (const float*)d_in[26];
  const float* gm_Whh    = (const float*)d_in[27];
  const float* gm_bih    = (const float*)d_in[28];
  const float* gm_bhh    = (const float*)d_in[29];

  const int n  = in_sizes[0];
  const int ne = in_sizes[1] / 2;
  const int* src = eidx;
  const int* dst = eidx + ne;

  // ---- workspace layout ----
  const size_t NH = (size_t)n * H;
  unsigned short* us = (unsigned short*)d_ws;
  unsigned short* x_bf = us;            // [N,H]
  unsigned short* t0   = us + NH;       // [N,H]
  unsigned short* t1   = us + 2*NH;     // [N,H]
  unsigned short* hb   = us + 3*NH;     // [N,H]
  unsigned short* gi   = us + 4*NH;     // [N,384]
  unsigned short* gh   = us + 7*NH;     // [N,384]
  float* fb = (float*)(us + 10*NH);
  float* rdot = fb;                     // [N]
  float* ssrc = rdot + n;               // [N]
  float* sdst = ssrc + n;               // [N]
  float* ealpha = sdst + n;             // [E]
  int* deg    = (int*)(ealpha + ne);    // [N]
  int* cursor = deg + n;                // [N]
  int* rowptr = cursor + n;             // [N+1]
  int* bsum   = rowptr + n + 1;         // [256]
  int* eid    = bsum + 256;             // [E]
  float* outraw = (float*)(eid + ne);   // [128]
  float* hidvec = outraw + 128;         // [128]
  float* cdstp  = hidvec + 128;         // [1]
  unsigned* gmax = (unsigned*)(cdstp + 1);
  float* gsum   = (float*)gmax + 1;
  float* numv   = gsum + 1;             // [128]
  float* w1col  = numv + 128;           // [128]
  // bf16 weight packs (16B-aligned: offset from ws start is even floats)
  unsigned short* wp = (unsigned short*)(w1col + 128);
  unsigned short* gW1bf  = wp;                 // 128*128
  unsigned short* gW2bf  = gW1bf  + 128*H;
  unsigned short* atomWbf= gW2bf  + 128*H;
  unsigned short* molWbf = atomWbf+ 128*H;
  unsigned short* g1ihbf = molWbf + 128*H;     // 384*128
  unsigned short* g1hhbf = g1ihbf + 384*H;
  unsigned short* g2ihbf = g1hhbf + 384*H;
  unsigned short* g2hhbf = g2ihbf + 384*H;

  const int nh_blocks  = (n*H + 255)/256;
  const int nb64       = (n + 63)/64;
  const int nwave4     = (n + 3)/4;
  const int e16_blocks = (ne + 15)/16;
  const int ethr       = (ne + 255)/256;
  const int nthr       = (n + 255)/256;
  const int nb         = (n + 255)/256;
  const int chunk      = (n + 255)/256;
  const int wcast128   = (128*H + 255)/256;
  const int wcast384   = (384*H + 255)/256;

  // ---- weight casts + CSR build + node init ----
  k_castw<<<wcast128,256,0,stream>>>(gate_W1, gW1bf, 128, 129);
  k_castw<<<wcast128,256,0,stream>>>(gate_W2, gW2bf, 128, 128);
  k_castw<<<wcast128,256,0,stream>>>(atom_W, atomWbf, 128, 128);
  k_castw<<<wcast128,256,0,stream>>>(mol_W, molWbf, 128, 128);
  k_castw<<<wcast384,256,0,stream>>>(g1_Wih, g1ihbf, 384, 128);
  k_castw<<<wcast384,256,0,stream>>>(g1_Whh, g1hhbf, 384, 128);
  k_castw<<<wcast384,256,0,stream>>>(g2_Wih, g2ihbf, 384, 128);
  k_castw<<<wcast384,256,0,stream>>>(g2_Whh, g2hhbf, 384, 128);
  k_pack_gate<<<1,128,0,stream>>>(gate_W1, w1col);
  k_node_init<<<nh_blocks,256,0,stream>>>(node_attr, W_lin1, b_lin1, x_bf, n);
  hipMemsetAsync(deg, 0, (size_t)n*4, stream);
  k_hist<<<ethr,256,0,stream>>>(dst, deg, ne);
  k_scan1<<<nb,256,0,stream>>>(deg, bsum, n);
  k_scan2<<<1,256,0,stream>>>(bsum, nb);
  k_scan3<<<nb,256,0,stream>>>(deg, bsum, rowptr, cursor, n);
  k_fill<<<ethr,256,0,stream>>>(dst, cursor, eid, ne);

  // ---- GATEConv ----
  k_gemm_mfma<<<dim3(nb64,1),256,0,stream>>>(x_bf, gW1bf, t0, n, H);   // xW1
  k_gemm_mfma<<<dim3(nb64,1),256,0,stream>>>(x_bf, gW2bf, t1, n, H);   // xW2
  k_rowdot2<<<nwave4,256,0,stream>>>(x_bf, gate_att_r, nullptr, rdot, nullptr, n);
  k_edge_logit_gate<<<e16_blocks,256,0,stream>>>(t0, w1col, gate_att_l, rdot, eattr,
                                                 src, dst, ealpha, ne);
  k_node_agg<<<nwave4,256,0,stream>>>(rowptr, eid, src, ealpha, t1, gate_b, hb, n);
  k_gemm_mfma<<<dim3(nb64,3),256,0,stream>>>(hb,   g1ihbf, gi, n, 384);
  k_gemm_mfma<<<dim3(nb64,3),256,0,stream>>>(x_bf, g1hhbf, gh, n, 384);
  k_gru_combine<<<nh_blocks,256,0,stream>>>(gi, gh, g1_bih, g1_bhh, x_bf, n);

  // ---- GATConv ----
  k_gemm_mfma<<<dim3(nb64,1),256,0,stream>>>(x_bf, atomWbf, t0, n, H); // xt
  k_rowdot2<<<nwave4,256,0,stream>>>(t0, atom_as, atom_ad, ssrc, sdst, n);
  k_node_agg_gat<<<nwave4,256,0,stream>>>(rowptr, eid, src, ssrc, sdst, t0, atom_b, hb, n);
  k_gemm_mfma<<<dim3(nb64,3),256,0,stream>>>(hb,   g2ihbf, gi, n, 384);
  k_gemm_mfma<<<dim3(nb64,3),256,0,stream>>>(x_bf, g2hhbf, gh, n, 384);
  k_gru_combine<<<nh_blocks,256,0,stream>>>(gi, gh, g2_bih, g2_bhh, x_bf, n);

  // ---- molecule readout ----
  hipMemsetAsync(outraw, 0, 128*4, stream);
  hipMemsetAsync(gmax, 0, 4, stream);
  hipMemsetAsync(gsum, 0, 4, stream);
  hipMemsetAsync(numv, 0, 128*4, stream);
  k_colsum<<<256,128,0,stream>>>(x_bf, outraw, n, chunk);
  k_mol_prep<<<1,128,0,stream>>>(outraw, mol_W, mol_ad, hidvec, cdstp);
  k_gemm_mfma<<<dim3(nb64,1),256,0,stream>>>(x_bf, molWbf, t1, n, H);  // xs
  k_rowdot2<<<nwave4,256,0,stream>>>(t1, mol_as, nullptr, rdot, nullptr, n);
  k_mol_logit<<<nthr,256,0,stream>>>(rdot, cdstp, gmax, n);
  k_mol_exp<<<nthr,256,0,stream>>>(rdot, gmax, gsum, n);
  k_mol_acc<<<256,128,0,stream>>>(t1, rdot, numv, n, chunk);
  k_mol_final<<<1,128,0,stream>>>(numv, gsum, mol_b, hidvec,
                                  gm_Wih, gm_Whh, gm_bih, gm_bhh, (float*)d_out);
}